// Round 16
// baseline (520.594 us; speedup 1.0000x reference)
//
#include <hip/hip_runtime.h>

// Problem constants
#define BB 4
#define TT 2048
#define CC 2048
#define NHEAD 16
#define DH 128
#define MM (BB * TT)          // 8192 rows
#define N3 (3 * CC)           // 6144
#define LD3 6144

typedef unsigned short u16;
typedef __attribute__((ext_vector_type(8))) short short8;
typedef __attribute__((ext_vector_type(4))) float f32x4;

__device__ __forceinline__ u16 f2bf(float f) {
  unsigned u = __float_as_uint(f);
  u += 0x7fffu + ((u >> 16) & 1u);      // RNE
  return (u16)(u >> 16);
}
__device__ __forceinline__ float bf2f(u16 h) {
  return __uint_as_float(((unsigned)h) << 16);
}

__device__ __forceinline__ void gload_lds16(const void* g, void* l) {
  __builtin_amdgcn_global_load_lds((const __attribute__((address_space(1))) void*)g,
                                   (__attribute__((address_space(3))) void*)l, 16, 0, 0);
}

__device__ __forceinline__ f32x4 mfma16(short8 a, short8 b, f32x4 c) {
  return __builtin_amdgcn_mfma_f32_16x16x32_bf16(a, b, c, 0, 0, 0);
}

// ---------------------------------------------------------------- convert x
__global__ void convert_x_kernel(const float* __restrict__ x, u16* __restrict__ xb) {
  const int total = (MM * CC) / 4;
  const float4* xv = (const float4*)x;
  ushort4* ov = (ushort4*)xb;
  for (int i = blockIdx.x * blockDim.x + threadIdx.x; i < total; i += gridDim.x * blockDim.x) {
    float4 v = xv[i];
    ushort4 o;
    o.x = f2bf(v.x); o.y = f2bf(v.y); o.z = f2bf(v.z); o.w = f2bf(v.w);
    ov[i] = o;
  }
}

// ------------------------------------------- transpose + convert W -> W^T bf16
__global__ void transpose_bf16_kernel(const float* __restrict__ W, u16* __restrict__ Wt,
                                      int rows, int cols) {
  __shared__ float tile[32][33];
  const int n0 = blockIdx.x * 32, k0 = blockIdx.y * 32;
  const int tx = threadIdx.x, ty = threadIdx.y;   // (32, 8)
  #pragma unroll
  for (int i = 0; i < 4; ++i)
    tile[ty + 8 * i][tx] = W[(size_t)(k0 + ty + 8 * i) * cols + n0 + tx];
  __syncthreads();
  #pragma unroll
  for (int i = 0; i < 4; ++i)
    Wt[(size_t)(n0 + ty + 8 * i) * rows + k0 + tx] = f2bf(tile[tx][ty + 8 * i]);
}

// ---------------------------------------------------------------- rope table
__global__ void rope_table_kernel(float2* __restrict__ tab) {
  int idx = blockIdx.x * 256 + threadIdx.x;     // T*64 entries
  int t = idx >> 6, f = idx & 63;
  float freq = expf(-0.14391156831f * (float)f);   // 10000^(-f/64)
  float ang = (float)t * freq;
  float s, c;
  sincosf(ang, &s, &c);
  tab[idx] = make_float2(c, s);
}

// ------------------------------------------------------------------- GEMM
// R16: 256x128 tile, BK=32, 8 waves (wave tile 128x32, acc 8x2), 3-deep
// circular LDS buffer (72 KB) -> 2 BLOCKS/CU (the R6->R7 attn lever:
// cross-block TLP hides the barrier convoy that intra-block schedules
// couldn't). launch_bounds(512,4) caps VGPR at 128 (16 waves/CU).
// Per K-tile: {stage(t+2) || 10 ds_reads ; MFMA 16 ; vmcnt(3) ; barrier}.
// FIFO: stage(t) published at end of t-1 (invariant: <=3 outstanding after
// each wait = stage(t+1)); WAR distance 3 buffers, barrier-separated.
// frow swizzle both-sides (64B rows): 8 consecutive rows -> 8 distinct
// 4-bank groups. Rope fused in epilogue: bcol[n]=n*64+wc*16 puts pair
// (c, c+64) in acc[m][0]/acc[m][1].
#define TA32 16384   // A tile: 256x32 bf16
#define TB32 8192    // B tile: 128x32 bf16

__device__ __forceinline__ int frow(int r) { return (r ^ (r >> 2)) & 3; }

__global__ __launch_bounds__(512, 4) void gemm_bt_256x128(
    const u16* __restrict__ A, const u16* __restrict__ Bt,
    void* __restrict__ Cout, const float2* __restrict__ tab,
    int K, int ldc, int out_bf16, int rope_mode) {
  __shared__ __align__(16) char As[3][TA32];
  __shared__ __align__(16) char Bs[3][TB32];
  const int tid = threadIdx.x;
  const int wid = tid >> 6, lane = tid & 63;
  const int l15 = lane & 15, g = lane >> 4;
  const int wr = wid >> 2, wc = wid & 3;          // 2M x 4N wave grid
  // T1 XCD swizzle (nwg % 8 == 0 for both call sites)
  const int nwg = gridDim.x * gridDim.y;
  const int orig = blockIdx.y * gridDim.x + blockIdx.x;
  const int swz = (orig & 7) * (nwg >> 3) + (orig >> 3);
  const int bx = swz % gridDim.x, by = swz / gridDim.x;
  const int row0 = by * 256, col0 = bx * 128;

  const u16* Ab = A + (size_t)row0 * K;
  const u16* Bb = Bt + (size_t)col0 * K;

  f32x4 acc[8][2];
  #pragma unroll
  for (int m = 0; m < 8; ++m) {
    acc[m][0] = (f32x4){0.f, 0.f, 0.f, 0.f};
    acc[m][1] = (f32x4){0.f, 0.f, 0.f, 0.f};
  }

  // fragment read offsets (swizzled; loop-invariant)
  int aoff[8], boff[2];
  #pragma unroll
  for (int m = 0; m < 8; ++m) {
    int r = wr * 128 + m * 16 + l15;
    aoff[m] = r * 64 + ((g ^ frow(r)) << 4);
  }
  #pragma unroll
  for (int n = 0; n < 2; ++n) {
    int r = n * 64 + wc * 16 + l15;
    boff[n] = r * 64 + ((g ^ frow(r)) << 4);
  }

  // staging descriptors: A = 1024 16B-chunks (2/thread), B = 512 (1/thread)
  const int chA0 = wid * 64 + lane, chA1 = 512 + chA0;
  const int rA0 = chA0 >> 2, sA0 = chA0 & 3;
  const int rA1 = chA1 >> 2, sA1 = chA1 & 3;
  const int rB = chA0 >> 2, sB = chA0 & 3;
  const size_t srcA0 = (size_t)rA0 * K + ((sA0 ^ frow(rA0)) << 3);
  const size_t srcA1 = (size_t)rA1 * K + ((sA1 ^ frow(rA1)) << 3);
  const size_t srcB  = (size_t)rB * K + ((sB ^ frow(rB)) << 3);
  const int dstA0 = (wid * 64) * 16;              // wave-uniform bases
  const int dstA1 = (512 + wid * 64) * 16;
  const int dstB  = (wid * 64) * 16;

  const int nt = K >> 5;                          // 64
  // ---- prologue: stage tiles 0,1 ; publish 0
  #pragma unroll
  for (int t = 0; t < 2; ++t) {
    const int k0 = t << 5;
    gload_lds16(Ab + srcA0 + k0, As[t] + dstA0);
    gload_lds16(Ab + srcA1 + k0, As[t] + dstA1);
    gload_lds16(Bb + srcB + k0, Bs[t] + dstB);
  }
  asm volatile("s_waitcnt vmcnt(3)" ::: "memory");
  __builtin_amdgcn_s_barrier();

  for (int t = 0; t < nt; ++t) {
    const char* At = As[t % 3];
    const char* Btl = Bs[t % 3];
    // ---- stage tile t+2 (early issue)
    if (t + 2 < nt) {
      const int k2 = (t + 2) << 5;
      char* Ad = As[(t + 2) % 3];
      char* Bd = Bs[(t + 2) % 3];
      gload_lds16(Ab + srcA0 + k2, Ad + dstA0);
      gload_lds16(Ab + srcA1 + k2, Ad + dstA1);
      gload_lds16(Bb + srcB + k2, Bd + dstB);
    }
    // ---- fragments + MFMA (split a-groups to cap VGPR liveness)
    short8 b0 = *(const short8*)(Btl + boff[0]);
    short8 b1 = *(const short8*)(Btl + boff[1]);
    short8 a4[4];
    #pragma unroll
    for (int mm = 0; mm < 4; ++mm) a4[mm] = *(const short8*)(At + aoff[mm]);
    __builtin_amdgcn_s_setprio(1);
    #pragma unroll
    for (int mm = 0; mm < 4; ++mm) {
      acc[mm][0] = mfma16(a4[mm], b0, acc[mm][0]);
      acc[mm][1] = mfma16(a4[mm], b1, acc[mm][1]);
    }
    __builtin_amdgcn_s_setprio(0);
    #pragma unroll
    for (int mm = 0; mm < 4; ++mm) a4[mm] = *(const short8*)(At + aoff[mm + 4]);
    __builtin_amdgcn_s_setprio(1);
    #pragma unroll
    for (int mm = 0; mm < 4; ++mm) {
      acc[mm + 4][0] = mfma16(a4[mm], b0, acc[mm + 4][0]);
      acc[mm + 4][1] = mfma16(a4[mm], b1, acc[mm + 4][1]);
    }
    __builtin_amdgcn_s_setprio(0);
    // ---- publish tile t+1 (counted; drains only at the tail)
    if (t + 2 < nt)      asm volatile("s_waitcnt vmcnt(3)" ::: "memory");
    else if (t + 1 < nt) asm volatile("s_waitcnt vmcnt(0)" ::: "memory");
    if (t + 1 < nt) __builtin_amdgcn_s_barrier();
  }

  // ---- epilogue
  if (out_bf16) {
    u16* Cb = (u16*)Cout;
    if (rope_mode && col0 < 4096) {
      // q/k tile: rotate in-register pairs acc[m][0] <-> acc[m][1]
      const float qs = (col0 < 2048) ? 0.08838834764831845f : 1.0f;
      const int colL = col0 + wc * 16 + l15;
      const int f = wc * 16 + l15;                // colL % 128, < 64
      #pragma unroll
      for (int m = 0; m < 8; ++m)
        #pragma unroll
        for (int j = 0; j < 4; ++j) {
          int row = row0 + wr * 128 + m * 16 + 4 * g + j;
          float2 cs = tab[((row & (TT - 1)) << 6) + f];
          float x1 = acc[m][0][j], x2 = acc[m][1][j];
          Cb[(size_t)row * ldc + colL] = f2bf((x1 * cs.x - x2 * cs.y) * qs);
          Cb[(size_t)row * ldc + colL + 64] = f2bf((x2 * cs.x + x1 * cs.y) * qs);
        }
    } else {
      #pragma unroll
      for (int m = 0; m < 8; ++m)
        #pragma unroll
        for (int n = 0; n < 2; ++n) {
          int col = col0 + n * 64 + wc * 16 + l15;
          #pragma unroll
          for (int j = 0; j < 4; ++j) {
            int row = row0 + wr * 128 + m * 16 + 4 * g + j;
            Cb[(size_t)row * ldc + col] = f2bf(acc[m][n][j]);
          }
        }
    }
  } else {
    float* Cf = (float*)Cout;
    #pragma unroll
    for (int m = 0; m < 8; ++m)
      #pragma unroll
      for (int n = 0; n < 2; ++n) {
        int col = col0 + n * 64 + wc * 16 + l15;
        #pragma unroll
        for (int j = 0; j < 4; ++j) {
          int row = row0 + wr * 128 + m * 16 + 4 * g + j;
          Cf[(size_t)row * ldc + col] = acc[m][n][j];
        }
      }
  }
}

// ---------------------------------------------------------------- attention
// QBLK=128, diagonal pairing (uniform 34 iters/block), 512 blocks, 2 blocks/CU.
// + T13 defer-max (THR=8).
#define QBLK 128
#define KBLK 64
#define PADV 72

__global__ __launch_bounds__(256, 2) void attn_kernel(const u16* __restrict__ qkv,
                                                      u16* __restrict__ y) {
  __shared__ __align__(16) u16 Ks[2][KBLK * 128];   // K tile (swizzled) / P buffer
  __shared__ __align__(16) u16 Vt[2][DH * PADV];    // V^T [d][kv], padded
  const int tid = threadIdx.x;
  const int wid = tid >> 6, lane = tid & 63;
  const int l15 = lane & 15, g = lane >> 4;
  const int b = blockIdx.y >> 4, h = blockIdx.y & 15;
  const size_t rb = (size_t)b * TT;
  const int vk0 = (tid & 15) * 4, vd0 = (tid >> 4) * 8;   // V-staging assignment

  for (int half = 0; half < 2; ++half) {
    const int qt0 = (half ? (15 - (int)blockIdx.x) : (int)blockIdx.x) * QBLK;

    // ---- Q fragments straight from global (one-time; rows 12KB apart)
    short8 qf[2][4];
    {
      const u16* qbase = qkv + (rb + qt0 + wid * 32 + l15) * LD3 + h * DH;
      #pragma unroll
      for (int f = 0; f < 2; ++f)
        #pragma unroll
        for (int kk = 0; kk < 4; ++kk)
          qf[f][kk] = *(const short8*)(qbase + f * 16 * LD3 + kk * 32 + g * 8);
    }

    // ---- prologue: stage K(tile0) -> Ks[0], V(tile0) -> Vt[0]
    {
      const u16* kbase = qkv + (rb)*LD3 + CC + h * DH;
      #pragma unroll
      for (int c = 0; c < 4; ++c) {
        int chunk = c * 256 + tid;
        int r = chunk >> 4, s = chunk & 15;
        gload_lds16(kbase + (size_t)r * LD3 + (size_t)((s ^ (r & 7)) * 8),
                    &Ks[0][(c * 256 + wid * 64) * 8]);
      }
      const u16* vg = qkv + (rb + vk0) * LD3 + 2 * CC + h * DH + vd0;
      short8 r0 = *(const short8*)vg;
      short8 r1 = *(const short8*)(vg + LD3);
      short8 r2 = *(const short8*)(vg + 2 * LD3);
      short8 r3 = *(const short8*)(vg + 3 * LD3);
      #pragma unroll
      for (int j = 0; j < 8; ++j) {
        ushort4 w;
        w.x = (u16)r0[j]; w.y = (u16)r1[j]; w.z = (u16)r2[j]; w.w = (u16)r3[j];
        *(ushort4*)&Vt[0][(vd0 + j) * PADV + vk0] = w;
      }
    }
    asm volatile("s_waitcnt vmcnt(0)" ::: "memory");
    __syncthreads();

    f32x4 o[2][8];
    float mrun[2][4], lrun[2][4];
    #pragma unroll
    for (int f = 0; f < 2; ++f) {
      #pragma unroll
      for (int nf = 0; nf < 8; ++nf) o[f][nf] = (f32x4){0.f, 0.f, 0.f, 0.f};
      #pragma unroll
      for (int j = 0; j < 4; ++j) { mrun[f][j] = -1e30f; lrun[f][j] = 0.f; }
    }

    const int nt = qt0 / KBLK + 2;         // kv tiles (last two intersect diagonal)
    for (int it = 0; it < nt; ++it) {
      const int cur = it & 1, nxt = cur ^ 1;
      const bool havenext = (it + 1) < nt;
      if (havenext) {
        const int kvn = (it + 1) * KBLK;
        const u16* kbase = qkv + (rb + kvn) * LD3 + CC + h * DH;
        #pragma unroll
        for (int c = 0; c < 4; ++c) {
          int chunk = c * 256 + tid;
          int r = chunk >> 4, s = chunk & 15;
          gload_lds16(kbase + (size_t)r * LD3 + (size_t)((s ^ (r & 7)) * 8),
                      &Ks[nxt][(c * 256 + wid * 64) * 8]);
        }
      }

      // ---- S = Q K^T from Ks[cur] (q pre-scaled by 1/sqrt(D))
      f32x4 s4[2][4];
      #pragma unroll
      for (int f = 0; f < 2; ++f)
        #pragma unroll
        for (int jf = 0; jf < 4; ++jf) s4[f][jf] = (f32x4){0.f, 0.f, 0.f, 0.f};
      #pragma unroll
      for (int jf = 0; jf < 4; ++jf) {
        int krow = jf * 16 + l15;
        #pragma unroll
        for (int kk = 0; kk < 4; ++kk) {
          short8 kf = *(const short8*)((const char*)Ks[cur] + krow * 256 +
                                       ((kk * 64 + g * 16) ^ ((l15 & 7) << 4)));
          s4[0][jf] = mfma16(qf[0][kk], kf, s4[0][jf]);
          s4[1][jf] = mfma16(qf[1][kk], kf, s4[1][jf]);
        }
      }
      // causal mask: last two tiles intersect the diagonal of this q-block
      if (it >= nt - 2) {
        const int kvb = it * KBLK - qt0;   // kv offset relative to q-block base
        #pragma unroll
        for (int f = 0; f < 2; ++f)
          #pragma unroll
          for (int jf = 0; jf < 4; ++jf)
            #pragma unroll
            for (int j = 0; j < 4; ++j)
              if (kvb + jf * 16 + l15 > wid * 32 + f * 16 + 4 * g + j)
                s4[f][jf][j] = -1e30f;
      }
      // ---- online softmax with T13 defer-max (THR=8)
      {
        float rmax[2][4];
        #pragma unroll
        for (int f = 0; f < 2; ++f) {
          #pragma unroll
          for (int j = 0; j < 4; ++j)
            rmax[f][j] = fmaxf(fmaxf(s4[f][0][j], s4[f][1][j]),
                               fmaxf(s4[f][2][j], s4[f][3][j]));
          #pragma unroll
          for (int j = 0; j < 4; ++j) {
            rmax[f][j] = fmaxf(rmax[f][j], __shfl_xor(rmax[f][j], 1, 64));
            rmax[f][j] = fmaxf(rmax[f][j], __shfl_xor(rmax[f][j], 2, 64));
            rmax[f][j] = fmaxf(rmax[f][j], __shfl_xor(rmax[f][j], 4, 64));
            rmax[f][j] = fmaxf(rmax[f][j], __shfl_xor(rmax[f][j], 8, 64));
          }
        }
        bool small = true;
        #pragma unroll
        for (int f = 0; f < 2; ++f)
          #pragma unroll
          for (int j = 0; j < 4; ++j)
            small = small && (rmax[f][j] <= mrun[f][j] + 8.0f);
        if (!__all((int)small)) {
          #pragma unroll
          for (int f = 0; f < 2; ++f)
            #pragma unroll
            for (int j = 0; j < 4; ++j) {
              float mn = fmaxf(mrun[f][j], rmax[f][j]);
              float corr = __expf(mrun[f][j] - mn);
              mrun[f][j] = mn;
              lrun[f][j] *= corr;
              #pragma unroll
              for (int nf = 0; nf < 8; ++nf) o[f][nf][j] *= corr;
            }
        }
        #pragma unroll
        for (int f = 0; f < 2; ++f) {
          float rsum[4];
          #pragma unroll
          for (int jf = 0; jf < 4; ++jf)
            #pragma unroll
            for (int j = 0; j < 4; ++j)
              s4[f][jf][j] = __expf(s4[f][jf][j] - mrun[f][j]);
          #pragma unroll
          for (int j = 0; j < 4; ++j) {
            rsum[j] = (s4[f][0][j] + s4[f][1][j]) + (s4[f][2][j] + s4[f][3][j]);
            rsum[j] += __shfl_xor(rsum[j], 1, 64);
            rsum[j] += __shfl_xor(rsum[j], 2, 64);
            rsum[j] += __shfl_xor(rsum[j], 4, 64);
            rsum[j] += __shfl_xor(rsum[j], 8, 64);
            lrun[f][j] += rsum[j];
          }
        }
      }

      // ---- all waves done reading K from Ks[cur]; reuse it as the P buffer
      __syncthreads();
      // P flat [128 q-rows][64 kv], G4 XOR swizzle: col ^= (row&7)<<3
      {
        u16* Pb = (u16*)Ks[cur];
        #pragma unroll
        for (int f = 0; f < 2; ++f)
          #pragma unroll
          for (int jf = 0; jf < 4; ++jf)
            #pragma unroll
            for (int j = 0; j < 4; ++j) {
              int prow = wid * 32 + f * 16 + 4 * g + j;
              int pcol = (jf * 16 + l15) ^ (((4 * g + j) & 7) << 3);
              Pb[prow * 64 + pcol] = f2bf(s4[f][jf][j]);
            }
      }
      asm volatile("s_waitcnt lgkmcnt(0)" ::: "memory");
      __builtin_amdgcn_sched_barrier(0);
      short8 pf[2][2];
      #pragma unroll
      for (int f = 0; f < 2; ++f)
        #pragma unroll
        for (int kk = 0; kk < 2; ++kk)
          pf[f][kk] = *(const short8*)&((const u16*)Ks[cur])[
              (wid * 32 + f * 16 + l15) * 64 + ((kk * 32 + g * 8) ^ ((l15 & 7) << 3))];

      // ---- O += P V from Vt[cur] (vf read shared across both fragments)
      #pragma unroll
      for (int nf = 0; nf < 8; ++nf) {
        #pragma unroll
        for (int kk = 0; kk < 2; ++kk) {
          short8 vf = *(const short8*)&Vt[cur][(nf * 16 + l15) * PADV + kk * 32 + g * 8];
          o[0][nf] = mfma16(pf[0][kk], vf, o[0][nf]);
          o[1][nf] = mfma16(pf[1][kk], vf, o[1][nf]);
        }
      }

      // ---- late V stage: load+transpose-write just before the drain
      if (havenext) {
        const int kvn = (it + 1) * KBLK;
        const u16* vg = qkv + (rb + kvn + vk0) * LD3 + 2 * CC + h * DH + vd0;
        short8 r0 = *(const short8*)vg;
        short8 r1 = *(const short8*)(vg + LD3);
        short8 r2 = *(const short8*)(vg + 2 * LD3);
        short8 r3 = *(const short8*)(vg + 3 * LD3);
        #pragma unroll
        for (int j = 0; j < 8; ++j) {
          ushort4 w;
          w.x = (u16)r0[j]; w.y = (u16)r1[j]; w.z = (u16)r2[j]; w.w = (u16)r3[j];
          *(ushort4*)&Vt[nxt][(vd0 + j) * PADV + vk0] = w;
        }
      }
      asm volatile("s_waitcnt vmcnt(0)" ::: "memory");
      __syncthreads();
    }

    // ---- write back this q-tile
    #pragma unroll
    for (int f = 0; f < 2; ++f) {
      float inv[4];
      #pragma unroll
      for (int j = 0; j < 4; ++j) inv[j] = 1.0f / lrun[f][j];
      #pragma unroll
      for (int nf = 0; nf < 8; ++nf)
        #pragma unroll
        for (int j = 0; j < 4; ++j)
          y[(rb + qt0 + wid * 32 + f * 16 + 4 * g + j) * CC + h * DH + nf * 16 + l15] =
              f2bf(o[f][nf][j] * inv[j]);
    }
  }
}

// ------------------------------------------------------------------ launch
// Workspace layout: non-aliased, 193 MB total.
extern "C" void kernel_launch(void* const* d_in, const int* in_sizes, int n_in,
                              void* d_out, int out_size, void* d_ws, size_t ws_size,
                              hipStream_t stream) {
  const float* x = (const float*)d_in[0];
  const float* Wqkv = (const float*)d_in[1];
  const float* Wproj = (const float*)d_in[2];
  char* ws = (char*)d_ws;
  u16* xb     = (u16*)(ws);                      // 32 MB
  u16* wqkvT  = (u16*)(ws + 33554432);           // 24 MB
  u16* wprojT = (u16*)(ws + 58720256);           // 8 MB
  u16* qkv    = (u16*)(ws + 67108864);           // 96 MB
  u16* y      = (u16*)(ws + 167772160);          // 32 MB
  float2* tab = (float2*)(ws + 201326592);       // 1 MB

  convert_x_kernel<<<4096, 256, 0, stream>>>(x, xb);
  transpose_bf16_kernel<<<dim3(192, 64), dim3(32, 8), 0, stream>>>(Wqkv, wqkvT, CC, N3);
  transpose_bf16_kernel<<<dim3(64, 64), dim3(32, 8), 0, stream>>>(Wproj, wprojT, CC, CC);
  rope_table_kernel<<<512, 256, 0, stream>>>(tab);
  gemm_bt_256x128<<<dim3(48, 32), 512, 0, stream>>>(xb, wqkvT, (void*)qkv, tab, CC, LD3, 1, 1);
  attn_kernel<<<dim3(8, 64), 256, 0, stream>>>(qkv, y);
  gemm_bt_256x128<<<dim3(16, 32), 512, 0, stream>>>(y, wprojT, d_out, tab, CC, CC, 0, 0);
}

// Round 17
// 478.989 us; speedup vs baseline: 1.0869x; 1.0869x over previous
//
#include <hip/hip_runtime.h>

// Problem constants
#define BB 4
#define TT 2048
#define CC 2048
#define NHEAD 16
#define DH 128
#define MM (BB * TT)          // 8192 rows
#define N3 (3 * CC)           // 6144
#define LD3 6144

typedef unsigned short u16;
typedef __attribute__((ext_vector_type(8))) short short8;
typedef __attribute__((ext_vector_type(4))) float f32x4;

__device__ __forceinline__ u16 f2bf(float f) {
  unsigned u = __float_as_uint(f);
  u += 0x7fffu + ((u >> 16) & 1u);      // RNE
  return (u16)(u >> 16);
}
__device__ __forceinline__ float bf2f(u16 h) {
  return __uint_as_float(((unsigned)h) << 16);
}

__device__ __forceinline__ void gload_lds16(const void* g, void* l) {
  __builtin_amdgcn_global_load_lds((const __attribute__((address_space(1))) void*)g,
                                   (__attribute__((address_space(3))) void*)l, 16, 0, 0);
}

__device__ __forceinline__ f32x4 mfma16(short8 a, short8 b, f32x4 c) {
  return __builtin_amdgcn_mfma_f32_16x16x32_bf16(a, b, c, 0, 0, 0);
}

// ---------------------------------------------------------------- convert x
__global__ void convert_x_kernel(const float* __restrict__ x, u16* __restrict__ xb) {
  const int total = (MM * CC) / 4;
  const float4* xv = (const float4*)x;
  ushort4* ov = (ushort4*)xb;
  for (int i = blockIdx.x * blockDim.x + threadIdx.x; i < total; i += gridDim.x * blockDim.x) {
    float4 v = xv[i];
    ushort4 o;
    o.x = f2bf(v.x); o.y = f2bf(v.y); o.z = f2bf(v.z); o.w = f2bf(v.w);
    ov[i] = o;
  }
}

// ------------------------------------------- transpose + convert W -> W^T bf16
__global__ void transpose_bf16_kernel(const float* __restrict__ W, u16* __restrict__ Wt,
                                      int rows, int cols) {
  __shared__ float tile[32][33];
  const int n0 = blockIdx.x * 32, k0 = blockIdx.y * 32;
  const int tx = threadIdx.x, ty = threadIdx.y;   // (32, 8)
  #pragma unroll
  for (int i = 0; i < 4; ++i)
    tile[ty + 8 * i][tx] = W[(size_t)(k0 + ty + 8 * i) * cols + n0 + tx];
  __syncthreads();
  #pragma unroll
  for (int i = 0; i < 4; ++i)
    Wt[(size_t)(n0 + ty + 8 * i) * rows + k0 + tx] = f2bf(tile[tx][ty + 8 * i]);
}

// ---------------------------------------------------------------- rope table
__global__ void rope_table_kernel(float2* __restrict__ tab) {
  int idx = blockIdx.x * 256 + threadIdx.x;     // T*64 entries
  int t = idx >> 6, f = idx & 63;
  float freq = expf(-0.14391156831f * (float)f);   // 10000^(-f/64)
  float ang = (float)t * freq;
  float s, c;
  sincosf(ang, &s, &c);
  tab[idx] = make_float2(c, s);
}

// ------------------------------------------------------------------- GEMM
// R15-exact: 256x256, 8 waves, BK=64, fine 4-phase interleave, swz47,
// T1 XCD swizzle, T5 setprio, rope fused in epilogue via pair-friendly
// B-column map bcol(n) (acc[m][n]/acc[m][n+2] are a rope pair in-register).
#define TILE_B 32768   // bytes of one [256][64]-bf16 LDS tile

__device__ __forceinline__ int swz47(int x) { return x ^ (((x >> 7) & 7) << 4); }

__device__ __forceinline__ void stage_chunk(const u16* __restrict__ src, int K, int k0,
                                            char* ldsTile, int kind, int wid, int lane) {
  // kind: 0=A-q1rows 1=A-q3rows 2=B-lo 3=B-hi ; 2 loads/thread = 16KB chunk
  #pragma unroll
  for (int c = 0; c < 2; ++c) {
    int x;
    if (kind < 2) {
      x = (kind ? 8192 : 0) + c * 16384 + wid * 1024 + lane * 16;
    } else {
      int wl = wid * 2 + c;
      x = ((kind == 3) ? 4096 : 0) + (wl >> 2) * 8192 + (wl & 3) * 1024 + lane * 16;
    }
    int l = swz47(x);                      // logical byte (involution, row-preserving)
    int r = l >> 7;                        // row 0..255
    int ce = (l >> 1) & 63;                // col element 0..63 (16B-aligned)
    gload_lds16(src + (size_t)r * K + k0 + ce, ldsTile + (x - lane * 16));
  }
}

__global__ __launch_bounds__(512, 2) void gemm_bt_256(const u16* __restrict__ A,
                                                      const u16* __restrict__ Bt,
                                                      void* __restrict__ Cout,
                                                      const float2* __restrict__ tab,
                                                      int K, int ldc, int out_bf16,
                                                      int rope_mode) {
  __shared__ __align__(16) char As[2][TILE_B];
  __shared__ __align__(16) char Bs[2][TILE_B];
  const int tid = threadIdx.x;
  const int wid = tid >> 6, lane = tid & 63;
  const int l15 = lane & 15, g = lane >> 4;
  const int wr = wid >> 2, wc = wid & 3;          // 2M x 4N wave grid
  // T1 XCD swizzle (nwg % 8 == 0 for both call sites)
  const int nwg = gridDim.x * gridDim.y;
  const int orig = blockIdx.y * gridDim.x + blockIdx.x;
  const int swz = (orig & 7) * (nwg >> 3) + (orig >> 3);
  const int bx = swz % gridDim.x, by = swz / gridDim.x;
  const int row0 = by * 256, col0 = bx * 256;

  const u16* Ab = A + (size_t)row0 * K;
  const u16* Bb = Bt + (size_t)col0 * K;

  f32x4 acc[8][4];
  #pragma unroll
  for (int m = 0; m < 8; ++m)
    #pragma unroll
    for (int n = 0; n < 4; ++n) acc[m][n] = (f32x4){0.f, 0.f, 0.f, 0.f};

  // pair-friendly B-column map
  int bcol[4];
  #pragma unroll
  for (int n = 0; n < 4; ++n)
    bcol[n] = (wc & 1) * 32 + (wc >> 1) * 128 + ((n >> 1) << 6) + ((n & 1) << 4);

  // per-thread logical byte bases for fragment reads
  const int abase = (wr * 128 + l15) * 128 + g * 16;   // + m*2048 + ks*64

  // ---- prologue: tile 0 fully staged into buf 0
  stage_chunk(Ab, K, 0, As[0], 0, wid, lane);
  stage_chunk(Bb, K, 0, Bs[0], 2, wid, lane);
  stage_chunk(Bb, K, 0, Bs[0], 3, wid, lane);
  stage_chunk(Ab, K, 0, As[0], 1, wid, lane);
  asm volatile("s_waitcnt vmcnt(0)" ::: "memory");
  __builtin_amdgcn_s_barrier();

  const int nt = K >> 6;
  short8 a[4][2], blo[2][2], bhi[2][2];
  for (int kt = 0; kt < nt; ++kt) {
    const int cur = kt & 1, nx = cur ^ 1;
    const bool hn = (kt + 1) < nt;
    const int kn = (kt + 1) << 6;
    const char* At = As[cur];
    const char* Btl = Bs[cur];

    // ======== phase 1: q1 (m0-3 x n0-1) ; stage kind0 of tile kt+1
    #pragma unroll
    for (int m = 0; m < 4; ++m)
      #pragma unroll
      for (int ks = 0; ks < 2; ++ks)
        a[m][ks] = *(const short8*)(At + swz47(abase + m * 2048 + ks * 64));
    #pragma unroll
    for (int n = 0; n < 2; ++n)
      #pragma unroll
      for (int ks = 0; ks < 2; ++ks)
        blo[n][ks] = *(const short8*)(Btl +
            swz47((bcol[n] + l15) * 128 + g * 16 + ks * 64));
    if (hn) stage_chunk(Ab, K, kn, As[nx], 0, wid, lane);
    __builtin_amdgcn_s_barrier();
    __builtin_amdgcn_s_setprio(1);
    #pragma unroll
    for (int m = 0; m < 4; ++m)
      #pragma unroll
      for (int n = 0; n < 2; ++n)
        #pragma unroll
        for (int ks = 0; ks < 2; ++ks)
          acc[m][n] = mfma16(a[m][ks], blo[n][ks], acc[m][n]);
    __builtin_amdgcn_s_setprio(0);
    if (hn) asm volatile("s_waitcnt vmcnt(4)" ::: "memory");
    else    asm volatile("s_waitcnt vmcnt(2)" ::: "memory");
    __builtin_amdgcn_s_barrier();

    // ======== phase 2: q2 (m0-3 x n2-3) ; stage kind2 (B-lo) of tile kt+1
    #pragma unroll
    for (int n = 0; n < 2; ++n)
      #pragma unroll
      for (int ks = 0; ks < 2; ++ks)
        bhi[n][ks] = *(const short8*)(Btl +
            swz47((bcol[n + 2] + l15) * 128 + g * 16 + ks * 64));
    if (hn) stage_chunk(Bb, K, kn, Bs[nx], 2, wid, lane);
    __builtin_amdgcn_s_barrier();
    __builtin_amdgcn_s_setprio(1);
    #pragma unroll
    for (int m = 0; m < 4; ++m)
      #pragma unroll
      for (int n = 0; n < 2; ++n)
        #pragma unroll
        for (int ks = 0; ks < 2; ++ks)
          acc[m][n + 2] = mfma16(a[m][ks], bhi[n][ks], acc[m][n + 2]);
    __builtin_amdgcn_s_setprio(0);
    if (hn) asm volatile("s_waitcnt vmcnt(4)" ::: "memory");
    else    asm volatile("s_waitcnt vmcnt(0)" ::: "memory");
    __builtin_amdgcn_s_barrier();

    // ======== phase 3: q3 (m4-7 x n0-1) ; stage kind3 (B-hi) of tile kt+1
    #pragma unroll
    for (int m = 0; m < 4; ++m)
      #pragma unroll
      for (int ks = 0; ks < 2; ++ks)
        a[m][ks] = *(const short8*)(At + swz47(abase + (m + 4) * 2048 + ks * 64));
    if (hn) stage_chunk(Bb, K, kn, Bs[nx], 3, wid, lane);
    __builtin_amdgcn_s_barrier();
    __builtin_amdgcn_s_setprio(1);
    #pragma unroll
    for (int m = 0; m < 4; ++m)
      #pragma unroll
      for (int n = 0; n < 2; ++n)
        #pragma unroll
        for (int ks = 0; ks < 2; ++ks)
          acc[m + 4][n] = mfma16(a[m][ks], blo[n][ks], acc[m + 4][n]);
    __builtin_amdgcn_s_setprio(0);
    if (hn) asm volatile("s_waitcnt vmcnt(4)" ::: "memory");
    __builtin_amdgcn_s_barrier();

    // ======== phase 4: q4 (m4-7 x n2-3) ; stage kind1 (A-q3rows) of tile kt+1
    if (hn) stage_chunk(Ab, K, kn, As[nx], 1, wid, lane);
    __builtin_amdgcn_s_barrier();
    __builtin_amdgcn_s_setprio(1);
    #pragma unroll
    for (int m = 0; m < 4; ++m)
      #pragma unroll
      for (int n = 0; n < 2; ++n)
        #pragma unroll
        for (int ks = 0; ks < 2; ++ks)
          acc[m + 4][n + 2] = mfma16(a[m][ks], bhi[n][ks], acc[m + 4][n + 2]);
    __builtin_amdgcn_s_setprio(0);
    if (hn) asm volatile("s_waitcnt vmcnt(4)" ::: "memory");
    __builtin_amdgcn_s_barrier();
  }

  // ---- epilogue
  if (out_bf16) {
    u16* Cb = (u16*)Cout;
    if (rope_mode && col0 < 4096) {
      // q or k tile: rotate pairs (n, n+2) in-register, then store
      const bool isq = (col0 < 2048);
      const float qs = isq ? 0.08838834764831845f : 1.0f;
      #pragma unroll
      for (int m = 0; m < 8; ++m)
        #pragma unroll
        for (int n = 0; n < 2; ++n) {
          int colL = col0 + bcol[n] + l15;
          int f = (wc & 1) * 32 + ((n & 1) << 4) + l15;   // = colL % 128, < 64
          #pragma unroll
          for (int j = 0; j < 4; ++j) {
            int row = row0 + wr * 128 + m * 16 + 4 * g + j;
            float2 cs = tab[((row & (TT - 1)) << 6) + f];
            float x1 = acc[m][n][j], x2 = acc[m][n + 2][j];
            float o1 = (x1 * cs.x - x2 * cs.y) * qs;
            float o2 = (x2 * cs.x + x1 * cs.y) * qs;
            Cb[(size_t)row * ldc + colL] = f2bf(o1);
            Cb[(size_t)row * ldc + colL + 64] = f2bf(o2);
          }
        }
    } else {
      #pragma unroll
      for (int m = 0; m < 8; ++m)
        #pragma unroll
        for (int n = 0; n < 4; ++n) {
          int row = row0 + wr * 128 + m * 16 + 4 * g;
          int col = col0 + bcol[n] + l15;
          #pragma unroll
          for (int j = 0; j < 4; ++j)
            Cb[(size_t)(row + j) * ldc + col] = f2bf(acc[m][n][j]);
        }
    }
  } else {
    float* Cf = (float*)Cout;
    #pragma unroll
    for (int m = 0; m < 8; ++m)
      #pragma unroll
      for (int n = 0; n < 4; ++n) {
        int row = row0 + wr * 128 + m * 16 + 4 * g;
        int col = col0 + bcol[n] + l15;
        #pragma unroll
        for (int j = 0; j < 4; ++j)
          Cf[(size_t)(row + j) * ldc + col] = acc[m][n][j];
      }
  }
}

// ---------------------------------------------------------------- attention
// QBLK=128, diagonal pairing, 512 blocks, 2 blocks/CU, T13 defer-max.
// R17: P round-trips through Vt[nxt] (dead V buffer) at the SAME row
// stride as Vt (PADV), making each wave's P region byte-identical to the
// rows its late-V stage writes -> fully wave-private -> the mid-iteration
// __syncthreads (which only protected Ks[cur] from P overwrite) is GONE.
// Order within a wave: P ds_write -> lgkmcnt(0)+sched_barrier -> pf ds_read
// -> PV -> late-V ds_write (overwrites P after pf is in regs; DS in-order).
#define QBLK 128
#define KBLK 64
#define PADV 72

__global__ __launch_bounds__(256, 2) void attn_kernel(const u16* __restrict__ qkv,
                                                      u16* __restrict__ y) {
  __shared__ __align__(16) u16 Ks[2][KBLK * 128];   // K tiles (swizzled)
  __shared__ __align__(16) u16 Vt[2][DH * PADV];    // V^T [d][kv] / P scratch
  const int tid = threadIdx.x;
  const int wid = tid >> 6, lane = tid & 63;
  const int l15 = lane & 15, g = lane >> 4;
  const int b = blockIdx.y >> 4, h = blockIdx.y & 15;
  const size_t rb = (size_t)b * TT;
  const int vk0 = (tid & 15) * 4, vd0 = (tid >> 4) * 8;   // V-staging assignment

  for (int half = 0; half < 2; ++half) {
    const int qt0 = (half ? (15 - (int)blockIdx.x) : (int)blockIdx.x) * QBLK;

    // ---- Q fragments straight from global (one-time; rows 12KB apart)
    short8 qf[2][4];
    {
      const u16* qbase = qkv + (rb + qt0 + wid * 32 + l15) * LD3 + h * DH;
      #pragma unroll
      for (int f = 0; f < 2; ++f)
        #pragma unroll
        for (int kk = 0; kk < 4; ++kk)
          qf[f][kk] = *(const short8*)(qbase + f * 16 * LD3 + kk * 32 + g * 8);
    }

    // ---- prologue: stage K(tile0) -> Ks[0], V(tile0) -> Vt[0]
    {
      const u16* kbase = qkv + (rb)*LD3 + CC + h * DH;
      #pragma unroll
      for (int c = 0; c < 4; ++c) {
        int chunk = c * 256 + tid;
        int r = chunk >> 4, s = chunk & 15;
        gload_lds16(kbase + (size_t)r * LD3 + (size_t)((s ^ (r & 7)) * 8),
                    &Ks[0][(c * 256 + wid * 64) * 8]);
      }
      const u16* vg = qkv + (rb + vk0) * LD3 + 2 * CC + h * DH + vd0;
      short8 r0 = *(const short8*)vg;
      short8 r1 = *(const short8*)(vg + LD3);
      short8 r2 = *(const short8*)(vg + 2 * LD3);
      short8 r3 = *(const short8*)(vg + 3 * LD3);
      #pragma unroll
      for (int j = 0; j < 8; ++j) {
        ushort4 w;
        w.x = (u16)r0[j]; w.y = (u16)r1[j]; w.z = (u16)r2[j]; w.w = (u16)r3[j];
        *(ushort4*)&Vt[0][(vd0 + j) * PADV + vk0] = w;
      }
    }
    asm volatile("s_waitcnt vmcnt(0)" ::: "memory");
    __syncthreads();

    f32x4 o[2][8];
    float mrun[2][4], lrun[2][4];
    #pragma unroll
    for (int f = 0; f < 2; ++f) {
      #pragma unroll
      for (int nf = 0; nf < 8; ++nf) o[f][nf] = (f32x4){0.f, 0.f, 0.f, 0.f};
      #pragma unroll
      for (int j = 0; j < 4; ++j) { mrun[f][j] = -1e30f; lrun[f][j] = 0.f; }
    }

    const int nt = qt0 / KBLK + 2;         // kv tiles (last two intersect diagonal)
    for (int it = 0; it < nt; ++it) {
      const int cur = it & 1, nxt = cur ^ 1;
      const bool havenext = (it + 1) < nt;
      if (havenext) {
        const int kvn = (it + 1) * KBLK;
        const u16* kbase = qkv + (rb + kvn) * LD3 + CC + h * DH;
        #pragma unroll
        for (int c = 0; c < 4; ++c) {
          int chunk = c * 256 + tid;
          int r = chunk >> 4, s = chunk & 15;
          gload_lds16(kbase + (size_t)r * LD3 + (size_t)((s ^ (r & 7)) * 8),
                      &Ks[nxt][(c * 256 + wid * 64) * 8]);
        }
      }

      // ---- S = Q K^T from Ks[cur] (q pre-scaled by 1/sqrt(D))
      f32x4 s4[2][4];
      #pragma unroll
      for (int f = 0; f < 2; ++f)
        #pragma unroll
        for (int jf = 0; jf < 4; ++jf) s4[f][jf] = (f32x4){0.f, 0.f, 0.f, 0.f};
      #pragma unroll
      for (int jf = 0; jf < 4; ++jf) {
        int krow = jf * 16 + l15;
        #pragma unroll
        for (int kk = 0; kk < 4; ++kk) {
          short8 kf = *(const short8*)((const char*)Ks[cur] + krow * 256 +
                                       ((kk * 64 + g * 16) ^ ((l15 & 7) << 4)));
          s4[0][jf] = mfma16(qf[0][kk], kf, s4[0][jf]);
          s4[1][jf] = mfma16(qf[1][kk], kf, s4[1][jf]);
        }
      }
      // causal mask: last two tiles intersect the diagonal of this q-block
      if (it >= nt - 2) {
        const int kvb = it * KBLK - qt0;   // kv offset relative to q-block base
        #pragma unroll
        for (int f = 0; f < 2; ++f)
          #pragma unroll
          for (int jf = 0; jf < 4; ++jf)
            #pragma unroll
            for (int j = 0; j < 4; ++j)
              if (kvb + jf * 16 + l15 > wid * 32 + f * 16 + 4 * g + j)
                s4[f][jf][j] = -1e30f;
      }
      // ---- online softmax with T13 defer-max (THR=8)
      {
        float rmax[2][4];
        #pragma unroll
        for (int f = 0; f < 2; ++f) {
          #pragma unroll
          for (int j = 0; j < 4; ++j)
            rmax[f][j] = fmaxf(fmaxf(s4[f][0][j], s4[f][1][j]),
                               fmaxf(s4[f][2][j], s4[f][3][j]));
          #pragma unroll
          for (int j = 0; j < 4; ++j) {
            rmax[f][j] = fmaxf(rmax[f][j], __shfl_xor(rmax[f][j], 1, 64));
            rmax[f][j] = fmaxf(rmax[f][j], __shfl_xor(rmax[f][j], 2, 64));
            rmax[f][j] = fmaxf(rmax[f][j], __shfl_xor(rmax[f][j], 4, 64));
            rmax[f][j] = fmaxf(rmax[f][j], __shfl_xor(rmax[f][j], 8, 64));
          }
        }
        bool small = true;
        #pragma unroll
        for (int f = 0; f < 2; ++f)
          #pragma unroll
          for (int j = 0; j < 4; ++j)
            small = small && (rmax[f][j] <= mrun[f][j] + 8.0f);
        if (!__all((int)small)) {
          #pragma unroll
          for (int f = 0; f < 2; ++f)
            #pragma unroll
            for (int j = 0; j < 4; ++j) {
              float mn = fmaxf(mrun[f][j], rmax[f][j]);
              float corr = __expf(mrun[f][j] - mn);
              mrun[f][j] = mn;
              lrun[f][j] *= corr;
              #pragma unroll
              for (int nf = 0; nf < 8; ++nf) o[f][nf][j] *= corr;
            }
        }
        #pragma unroll
        for (int f = 0; f < 2; ++f) {
          float rsum[4];
          #pragma unroll
          for (int jf = 0; jf < 4; ++jf)
            #pragma unroll
            for (int j = 0; j < 4; ++j)
              s4[f][jf][j] = __expf(s4[f][jf][j] - mrun[f][j]);
          #pragma unroll
          for (int j = 0; j < 4; ++j) {
            rsum[j] = (s4[f][0][j] + s4[f][1][j]) + (s4[f][2][j] + s4[f][3][j]);
            rsum[j] += __shfl_xor(rsum[j], 1, 64);
            rsum[j] += __shfl_xor(rsum[j], 2, 64);
            rsum[j] += __shfl_xor(rsum[j], 4, 64);
            rsum[j] += __shfl_xor(rsum[j], 8, 64);
            lrun[f][j] += rsum[j];
          }
        }
      }

      // ---- P -> Vt[nxt] (wave-private rows; NO barrier needed)
      // P row r (q-row within block) at Vt[nxt] + r*PADV, cols 0..63,
      // G4 XOR swizzle on col: pcol ^= ((r&7)<<3)
      {
        u16* Pb = (u16*)Vt[nxt];
        #pragma unroll
        for (int f = 0; f < 2; ++f)
          #pragma unroll
          for (int jf = 0; jf < 4; ++jf)
            #pragma unroll
            for (int j = 0; j < 4; ++j) {
              int prow = wid * 32 + f * 16 + 4 * g + j;
              int pcol = (jf * 16 + l15) ^ (((4 * g + j) & 7) << 3);
              Pb[prow * PADV + pcol] = f2bf(s4[f][jf][j]);
            }
      }
      asm volatile("s_waitcnt lgkmcnt(0)" ::: "memory");
      __builtin_amdgcn_sched_barrier(0);
      short8 pf[2][2];
      #pragma unroll
      for (int f = 0; f < 2; ++f)
        #pragma unroll
        for (int kk = 0; kk < 2; ++kk)
          pf[f][kk] = *(const short8*)&((const u16*)Vt[nxt])[
              (wid * 32 + f * 16 + l15) * PADV + ((kk * 32 + g * 8) ^ ((l15 & 7) << 3))];

      // ---- O += P V from Vt[cur] (vf read shared across both fragments)
      #pragma unroll
      for (int nf = 0; nf < 8; ++nf) {
        #pragma unroll
        for (int kk = 0; kk < 2; ++kk) {
          short8 vf = *(const short8*)&Vt[cur][(nf * 16 + l15) * PADV + kk * 32 + g * 8];
          o[0][nf] = mfma16(pf[0][kk], vf, o[0][nf]);
          o[1][nf] = mfma16(pf[1][kk], vf, o[1][nf]);
        }
      }

      // ---- late V stage into Vt[nxt] (overwrites this wave's P rows —
      // safe: pf already in registers, same-wave DS is in-order)
      if (havenext) {
        const int kvn = (it + 1) * KBLK;
        const u16* vg = qkv + (rb + kvn + vk0) * LD3 + 2 * CC + h * DH + vd0;
        short8 r0 = *(const short8*)vg;
        short8 r1 = *(const short8*)(vg + LD3);
        short8 r2 = *(const short8*)(vg + 2 * LD3);
        short8 r3 = *(const short8*)(vg + 3 * LD3);
        #pragma unroll
        for (int j = 0; j < 8; ++j) {
          ushort4 w;
          w.x = (u16)r0[j]; w.y = (u16)r1[j]; w.z = (u16)r2[j]; w.w = (u16)r3[j];
          *(ushort4*)&Vt[nxt][(vd0 + j) * PADV + vk0] = w;
        }
      }
      asm volatile("s_waitcnt vmcnt(0)" ::: "memory");
      __syncthreads();
    }

    // ---- write back this q-tile
    #pragma unroll
    for (int f = 0; f < 2; ++f) {
      float inv[4];
      #pragma unroll
      for (int j = 0; j < 4; ++j) inv[j] = 1.0f / lrun[f][j];
      #pragma unroll
      for (int nf = 0; nf < 8; ++nf)
        #pragma unroll
        for (int j = 0; j < 4; ++j)
          y[(rb + qt0 + wid * 32 + f * 16 + 4 * g + j) * CC + h * DH + nf * 16 + l15] =
              f2bf(o[f][nf][j] * inv[j]);
    }
  }
}

// ------------------------------------------------------------------ launch
// Workspace layout: non-aliased, 193 MB total.
extern "C" void kernel_launch(void* const* d_in, const int* in_sizes, int n_in,
                              void* d_out, int out_size, void* d_ws, size_t ws_size,
                              hipStream_t stream) {
  const float* x = (const float*)d_in[0];
  const float* Wqkv = (const float*)d_in[1];
  const float* Wproj = (const float*)d_in[2];
  char* ws = (char*)d_ws;
  u16* xb     = (u16*)(ws);                      // 32 MB
  u16* wqkvT  = (u16*)(ws + 33554432);           // 24 MB
  u16* wprojT = (u16*)(ws + 58720256);           // 8 MB
  u16* qkv    = (u16*)(ws + 67108864);           // 96 MB
  u16* y      = (u16*)(ws + 167772160);          // 32 MB
  float2* tab = (float2*)(ws + 201326592);       // 1 MB

  convert_x_kernel<<<4096, 256, 0, stream>>>(x, xb);
  transpose_bf16_kernel<<<dim3(192, 64), dim3(32, 8), 0, stream>>>(Wqkv, wqkvT, CC, N3);
  transpose_bf16_kernel<<<dim3(64, 64), dim3(32, 8), 0, stream>>>(Wproj, wprojT, CC, CC);
  rope_table_kernel<<<512, 256, 0, stream>>>(tab);
  gemm_bt_256<<<dim3(24, 32), 512, 0, stream>>>(xb, wqkvT, (void*)qkv, tab, CC, LD3, 1, 1);
  attn_kernel<<<dim3(8, 64), 256, 0, stream>>>(qkv, y);
  gemm_bt_256<<<dim3(8, 32), 512, 0, stream>>>(y, wprojT, d_out, tab, CC, CC, 0, 0);
}

// Round 18
// 477.414 us; speedup vs baseline: 1.0904x; 1.0033x over previous
//
#include <hip/hip_runtime.h>

// Problem constants
#define BB 4
#define TT 2048
#define CC 2048
#define NHEAD 16
#define DH 128
#define MM (BB * TT)          // 8192 rows
#define N3 (3 * CC)           // 6144
#define LD3 6144

typedef unsigned short u16;
typedef __attribute__((ext_vector_type(8))) short short8;
typedef __attribute__((ext_vector_type(4))) float f32x4;

__device__ __forceinline__ u16 f2bf(float f) {
  unsigned u = __float_as_uint(f);
  u += 0x7fffu + ((u >> 16) & 1u);      // RNE
  return (u16)(u >> 16);
}
__device__ __forceinline__ float bf2f(u16 h) {
  return __uint_as_float(((unsigned)h) << 16);
}

__device__ __forceinline__ void gload_lds16(const void* g, void* l) {
  __builtin_amdgcn_global_load_lds((const __attribute__((address_space(1))) void*)g,
                                   (__attribute__((address_space(3))) void*)l, 16, 0, 0);
}

__device__ __forceinline__ f32x4 mfma16(short8 a, short8 b, f32x4 c) {
  return __builtin_amdgcn_mfma_f32_16x16x32_bf16(a, b, c, 0, 0, 0);
}

// ---------------------------------------------------------------- convert x
__global__ void convert_x_kernel(const float* __restrict__ x, u16* __restrict__ xb) {
  const int total = (MM * CC) / 4;
  const float4* xv = (const float4*)x;
  ushort4* ov = (ushort4*)xb;
  for (int i = blockIdx.x * blockDim.x + threadIdx.x; i < total; i += gridDim.x * blockDim.x) {
    float4 v = xv[i];
    ushort4 o;
    o.x = f2bf(v.x); o.y = f2bf(v.y); o.z = f2bf(v.z); o.w = f2bf(v.w);
    ov[i] = o;
  }
}

// ------------------------------------------- transpose + convert W -> W^T bf16
__global__ void transpose_bf16_kernel(const float* __restrict__ W, u16* __restrict__ Wt,
                                      int rows, int cols) {
  __shared__ float tile[32][33];
  const int n0 = blockIdx.x * 32, k0 = blockIdx.y * 32;
  const int tx = threadIdx.x, ty = threadIdx.y;   // (32, 8)
  #pragma unroll
  for (int i = 0; i < 4; ++i)
    tile[ty + 8 * i][tx] = W[(size_t)(k0 + ty + 8 * i) * cols + n0 + tx];
  __syncthreads();
  #pragma unroll
  for (int i = 0; i < 4; ++i)
    Wt[(size_t)(n0 + ty + 8 * i) * rows + k0 + tx] = f2bf(tile[tx][ty + 8 * i]);
}

// ---------------------------------------------------------------- rope table
__global__ void rope_table_kernel(float2* __restrict__ tab) {
  int idx = blockIdx.x * 256 + threadIdx.x;     // T*64 entries
  int t = idx >> 6, f = idx & 63;
  float freq = expf(-0.14391156831f * (float)f);   // 10000^(-f/64)
  float ang = (float)t * freq;
  float s, c;
  sincosf(ang, &s, &c);
  tab[idx] = make_float2(c, s);
}

// ------------------------------------------------------------------- GEMM
// R15 structure + R18: XCD OWNERSHIP remap (vs flat T1 swizzle). Each XCD
// owns a contiguous 4-row by-band (A panel = 4 MB = one XCD L2); bx iterated
// within the band so B streams L3-resident. Rationale: this schedule's
// vmcnt(4) publishes chunks issued only ~2 phases (~550 cy) earlier; at HBM
// latency (~900 cy, FETCH=368MB mostly-miss) that's a ~300 cy stall per
// phase. L2/L3 hits (200-400 cy) should eliminate it. (R11's null was on a
// 3-deep pipeline with ~1000 cy cover — latency was already hidden there.)
#define TILE_B 32768   // bytes of one [256][64]-bf16 LDS tile

__device__ __forceinline__ int swz47(int x) { return x ^ (((x >> 7) & 7) << 4); }

__device__ __forceinline__ void stage_chunk(const u16* __restrict__ src, int K, int k0,
                                            char* ldsTile, int kind, int wid, int lane) {
  // kind: 0=A-q1rows 1=A-q3rows 2=B-lo 3=B-hi ; 2 loads/thread = 16KB chunk
  #pragma unroll
  for (int c = 0; c < 2; ++c) {
    int x;
    if (kind < 2) {
      x = (kind ? 8192 : 0) + c * 16384 + wid * 1024 + lane * 16;
    } else {
      int wl = wid * 2 + c;
      x = ((kind == 3) ? 4096 : 0) + (wl >> 2) * 8192 + (wl & 3) * 1024 + lane * 16;
    }
    int l = swz47(x);                      // logical byte (involution, row-preserving)
    int r = l >> 7;                        // row 0..255
    int ce = (l >> 1) & 63;                // col element 0..63 (16B-aligned)
    gload_lds16(src + (size_t)r * K + k0 + ce, ldsTile + (x - lane * 16));
  }
}

__global__ __launch_bounds__(512, 2) void gemm_bt_256(const u16* __restrict__ A,
                                                      const u16* __restrict__ Bt,
                                                      void* __restrict__ Cout,
                                                      const float2* __restrict__ tab,
                                                      int K, int ldc, int out_bf16,
                                                      int rope_mode) {
  __shared__ __align__(16) char As[2][TILE_B];
  __shared__ __align__(16) char Bs[2][TILE_B];
  const int tid = threadIdx.x;
  const int wid = tid >> 6, lane = tid & 63;
  const int l15 = lane & 15, g = lane >> 4;
  const int wr = wid >> 2, wc = wid & 3;          // 2M x 4N wave grid
  // XCD ownership remap (bijective; gridDim.y % 8 == 0 at both call sites)
  const int orig = blockIdx.y * gridDim.x + blockIdx.x;
  const int xcd = orig & 7;
  const int local = orig >> 3;
  const int gy = gridDim.y >> 3;                  // by-rows per XCD (=4)
  const int bx = local / gy;
  const int by = xcd * gy + (local - bx * gy);
  const int row0 = by * 256, col0 = bx * 256;

  const u16* Ab = A + (size_t)row0 * K;
  const u16* Bb = Bt + (size_t)col0 * K;

  f32x4 acc[8][4];
  #pragma unroll
  for (int m = 0; m < 8; ++m)
    #pragma unroll
    for (int n = 0; n < 4; ++n) acc[m][n] = (f32x4){0.f, 0.f, 0.f, 0.f};

  // pair-friendly B-column map
  int bcol[4];
  #pragma unroll
  for (int n = 0; n < 4; ++n)
    bcol[n] = (wc & 1) * 32 + (wc >> 1) * 128 + ((n >> 1) << 6) + ((n & 1) << 4);

  // per-thread logical byte bases for fragment reads
  const int abase = (wr * 128 + l15) * 128 + g * 16;   // + m*2048 + ks*64

  // ---- prologue: tile 0 fully staged into buf 0
  stage_chunk(Ab, K, 0, As[0], 0, wid, lane);
  stage_chunk(Bb, K, 0, Bs[0], 2, wid, lane);
  stage_chunk(Bb, K, 0, Bs[0], 3, wid, lane);
  stage_chunk(Ab, K, 0, As[0], 1, wid, lane);
  asm volatile("s_waitcnt vmcnt(0)" ::: "memory");
  __builtin_amdgcn_s_barrier();

  const int nt = K >> 6;
  short8 a[4][2], blo[2][2], bhi[2][2];
  for (int kt = 0; kt < nt; ++kt) {
    const int cur = kt & 1, nx = cur ^ 1;
    const bool hn = (kt + 1) < nt;
    const int kn = (kt + 1) << 6;
    const char* At = As[cur];
    const char* Btl = Bs[cur];

    // ======== phase 1: q1 (m0-3 x n0-1) ; stage kind0 of tile kt+1
    #pragma unroll
    for (int m = 0; m < 4; ++m)
      #pragma unroll
      for (int ks = 0; ks < 2; ++ks)
        a[m][ks] = *(const short8*)(At + swz47(abase + m * 2048 + ks * 64));
    #pragma unroll
    for (int n = 0; n < 2; ++n)
      #pragma unroll
      for (int ks = 0; ks < 2; ++ks)
        blo[n][ks] = *(const short8*)(Btl +
            swz47((bcol[n] + l15) * 128 + g * 16 + ks * 64));
    if (hn) stage_chunk(Ab, K, kn, As[nx], 0, wid, lane);
    __builtin_amdgcn_s_barrier();
    __builtin_amdgcn_s_setprio(1);
    #pragma unroll
    for (int m = 0; m < 4; ++m)
      #pragma unroll
      for (int n = 0; n < 2; ++n)
        #pragma unroll
        for (int ks = 0; ks < 2; ++ks)
          acc[m][n] = mfma16(a[m][ks], blo[n][ks], acc[m][n]);
    __builtin_amdgcn_s_setprio(0);
    if (hn) asm volatile("s_waitcnt vmcnt(4)" ::: "memory");
    else    asm volatile("s_waitcnt vmcnt(2)" ::: "memory");
    __builtin_amdgcn_s_barrier();

    // ======== phase 2: q2 (m0-3 x n2-3) ; stage kind2 (B-lo) of tile kt+1
    #pragma unroll
    for (int n = 0; n < 2; ++n)
      #pragma unroll
      for (int ks = 0; ks < 2; ++ks)
        bhi[n][ks] = *(const short8*)(Btl +
            swz47((bcol[n + 2] + l15) * 128 + g * 16 + ks * 64));
    if (hn) stage_chunk(Bb, K, kn, Bs[nx], 2, wid, lane);
    __builtin_amdgcn_s_barrier();
    __builtin_amdgcn_s_setprio(1);
    #pragma unroll
    for (int m = 0; m < 4; ++m)
      #pragma unroll
      for (int n = 0; n < 2; ++n)
        #pragma unroll
        for (int ks = 0; ks < 2; ++ks)
          acc[m][n + 2] = mfma16(a[m][ks], bhi[n][ks], acc[m][n + 2]);
    __builtin_amdgcn_s_setprio(0);
    if (hn) asm volatile("s_waitcnt vmcnt(4)" ::: "memory");
    else    asm volatile("s_waitcnt vmcnt(0)" ::: "memory");
    __builtin_amdgcn_s_barrier();

    // ======== phase 3: q3 (m4-7 x n0-1) ; stage kind3 (B-hi) of tile kt+1
    #pragma unroll
    for (int m = 0; m < 4; ++m)
      #pragma unroll
      for (int ks = 0; ks < 2; ++ks)
        a[m][ks] = *(const short8*)(At + swz47(abase + (m + 4) * 2048 + ks * 64));
    if (hn) stage_chunk(Bb, K, kn, Bs[nx], 3, wid, lane);
    __builtin_amdgcn_s_barrier();
    __builtin_amdgcn_s_setprio(1);
    #pragma unroll
    for (int m = 0; m < 4; ++m)
      #pragma unroll
      for (int n = 0; n < 2; ++n)
        #pragma unroll
        for (int ks = 0; ks < 2; ++ks)
          acc[m + 4][n] = mfma16(a[m][ks], blo[n][ks], acc[m + 4][n]);
    __builtin_amdgcn_s_setprio(0);
    if (hn) asm volatile("s_waitcnt vmcnt(4)" ::: "memory");
    __builtin_amdgcn_s_barrier();

    // ======== phase 4: q4 (m4-7 x n2-3) ; stage kind1 (A-q3rows) of tile kt+1
    if (hn) stage_chunk(Ab, K, kn, As[nx], 1, wid, lane);
    __builtin_amdgcn_s_barrier();
    __builtin_amdgcn_s_setprio(1);
    #pragma unroll
    for (int m = 0; m < 4; ++m)
      #pragma unroll
      for (int n = 0; n < 2; ++n)
        #pragma unroll
        for (int ks = 0; ks < 2; ++ks)
          acc[m + 4][n + 2] = mfma16(a[m][ks], bhi[n][ks], acc[m + 4][n + 2]);
    __builtin_amdgcn_s_setprio(0);
    if (hn) asm volatile("s_waitcnt vmcnt(4)" ::: "memory");
    __builtin_amdgcn_s_barrier();
  }

  // ---- epilogue
  if (out_bf16) {
    u16* Cb = (u16*)Cout;
    if (rope_mode && col0 < 4096) {
      // q or k tile: rotate pairs (n, n+2) in-register, then store
      const bool isq = (col0 < 2048);
      const float qs = isq ? 0.08838834764831845f : 1.0f;
      #pragma unroll
      for (int m = 0; m < 8; ++m)
        #pragma unroll
        for (int n = 0; n < 2; ++n) {
          int colL = col0 + bcol[n] + l15;
          int f = (wc & 1) * 32 + ((n & 1) << 4) + l15;   // = colL % 128, < 64
          #pragma unroll
          for (int j = 0; j < 4; ++j) {
            int row = row0 + wr * 128 + m * 16 + 4 * g + j;
            float2 cs = tab[((row & (TT - 1)) << 6) + f];
            float x1 = acc[m][n][j], x2 = acc[m][n + 2][j];
            float o1 = (x1 * cs.x - x2 * cs.y) * qs;
            float o2 = (x2 * cs.x + x1 * cs.y) * qs;
            Cb[(size_t)row * ldc + colL] = f2bf(o1);
            Cb[(size_t)row * ldc + colL + 64] = f2bf(o2);
          }
        }
    } else {
      #pragma unroll
      for (int m = 0; m < 8; ++m)
        #pragma unroll
        for (int n = 0; n < 4; ++n) {
          int row = row0 + wr * 128 + m * 16 + 4 * g;
          int col = col0 + bcol[n] + l15;
          #pragma unroll
          for (int j = 0; j < 4; ++j)
            Cb[(size_t)(row + j) * ldc + col] = f2bf(acc[m][n][j]);
        }
    }
  } else {
    float* Cf = (float*)Cout;
    #pragma unroll
    for (int m = 0; m < 8; ++m)
      #pragma unroll
      for (int n = 0; n < 4; ++n) {
        int row = row0 + wr * 128 + m * 16 + 4 * g;
        int col = col0 + bcol[n] + l15;
        #pragma unroll
        for (int j = 0; j < 4; ++j)
          Cf[(size_t)(row + j) * ldc + col] = acc[m][n][j];
      }
  }
}

// ---------------------------------------------------------------- attention
// R17-exact: QBLK=128, diagonal pairing, 512 blocks, 2 blocks/CU, T13
// defer-max, P round-trips through Vt[nxt] (wave-private rows; 2 barriers/iter).
#define QBLK 128
#define KBLK 64
#define PADV 72

__global__ __launch_bounds__(256, 2) void attn_kernel(const u16* __restrict__ qkv,
                                                      u16* __restrict__ y) {
  __shared__ __align__(16) u16 Ks[2][KBLK * 128];   // K tiles (swizzled)
  __shared__ __align__(16) u16 Vt[2][DH * PADV];    // V^T [d][kv] / P scratch
  const int tid = threadIdx.x;
  const int wid = tid >> 6, lane = tid & 63;
  const int l15 = lane & 15, g = lane >> 4;
  const int b = blockIdx.y >> 4, h = blockIdx.y & 15;
  const size_t rb = (size_t)b * TT;
  const int vk0 = (tid & 15) * 4, vd0 = (tid >> 4) * 8;   // V-staging assignment

  for (int half = 0; half < 2; ++half) {
    const int qt0 = (half ? (15 - (int)blockIdx.x) : (int)blockIdx.x) * QBLK;

    // ---- Q fragments straight from global (one-time; rows 12KB apart)
    short8 qf[2][4];
    {
      const u16* qbase = qkv + (rb + qt0 + wid * 32 + l15) * LD3 + h * DH;
      #pragma unroll
      for (int f = 0; f < 2; ++f)
        #pragma unroll
        for (int kk = 0; kk < 4; ++kk)
          qf[f][kk] = *(const short8*)(qbase + f * 16 * LD3 + kk * 32 + g * 8);
    }

    // ---- prologue: stage K(tile0) -> Ks[0], V(tile0) -> Vt[0]
    {
      const u16* kbase = qkv + (rb)*LD3 + CC + h * DH;
      #pragma unroll
      for (int c = 0; c < 4; ++c) {
        int chunk = c * 256 + tid;
        int r = chunk >> 4, s = chunk & 15;
        gload_lds16(kbase + (size_t)r * LD3 + (size_t)((s ^ (r & 7)) * 8),
                    &Ks[0][(c * 256 + wid * 64) * 8]);
      }
      const u16* vg = qkv + (rb + vk0) * LD3 + 2 * CC + h * DH + vd0;
      short8 r0 = *(const short8*)vg;
      short8 r1 = *(const short8*)(vg + LD3);
      short8 r2 = *(const short8*)(vg + 2 * LD3);
      short8 r3 = *(const short8*)(vg + 3 * LD3);
      #pragma unroll
      for (int j = 0; j < 8; ++j) {
        ushort4 w;
        w.x = (u16)r0[j]; w.y = (u16)r1[j]; w.z = (u16)r2[j]; w.w = (u16)r3[j];
        *(ushort4*)&Vt[0][(vd0 + j) * PADV + vk0] = w;
      }
    }
    asm volatile("s_waitcnt vmcnt(0)" ::: "memory");
    __syncthreads();

    f32x4 o[2][8];
    float mrun[2][4], lrun[2][4];
    #pragma unroll
    for (int f = 0; f < 2; ++f) {
      #pragma unroll
      for (int nf = 0; nf < 8; ++nf) o[f][nf] = (f32x4){0.f, 0.f, 0.f, 0.f};
      #pragma unroll
      for (int j = 0; j < 4; ++j) { mrun[f][j] = -1e30f; lrun[f][j] = 0.f; }
    }

    const int nt = qt0 / KBLK + 2;         // kv tiles (last two intersect diagonal)
    for (int it = 0; it < nt; ++it) {
      const int cur = it & 1, nxt = cur ^ 1;
      const bool havenext = (it + 1) < nt;
      if (havenext) {
        const int kvn = (it + 1) * KBLK;
        const u16* kbase = qkv + (rb + kvn) * LD3 + CC + h * DH;
        #pragma unroll
        for (int c = 0; c < 4; ++c) {
          int chunk = c * 256 + tid;
          int r = chunk >> 4, s = chunk & 15;
          gload_lds16(kbase + (size_t)r * LD3 + (size_t)((s ^ (r & 7)) * 8),
                      &Ks[nxt][(c * 256 + wid * 64) * 8]);
        }
      }

      // ---- S = Q K^T from Ks[cur] (q pre-scaled by 1/sqrt(D))
      f32x4 s4[2][4];
      #pragma unroll
      for (int f = 0; f < 2; ++f)
        #pragma unroll
        for (int jf = 0; jf < 4; ++jf) s4[f][jf] = (f32x4){0.f, 0.f, 0.f, 0.f};
      #pragma unroll
      for (int jf = 0; jf < 4; ++jf) {
        int krow = jf * 16 + l15;
        #pragma unroll
        for (int kk = 0; kk < 4; ++kk) {
          short8 kf = *(const short8*)((const char*)Ks[cur] + krow * 256 +
                                       ((kk * 64 + g * 16) ^ ((l15 & 7) << 4)));
          s4[0][jf] = mfma16(qf[0][kk], kf, s4[0][jf]);
          s4[1][jf] = mfma16(qf[1][kk], kf, s4[1][jf]);
        }
      }
      // causal mask: last two tiles intersect the diagonal of this q-block
      if (it >= nt - 2) {
        const int kvb = it * KBLK - qt0;   // kv offset relative to q-block base
        #pragma unroll
        for (int f = 0; f < 2; ++f)
          #pragma unroll
          for (int jf = 0; jf < 4; ++jf)
            #pragma unroll
            for (int j = 0; j < 4; ++j)
              if (kvb + jf * 16 + l15 > wid * 32 + f * 16 + 4 * g + j)
                s4[f][jf][j] = -1e30f;
      }
      // ---- online softmax with T13 defer-max (THR=8)
      {
        float rmax[2][4];
        #pragma unroll
        for (int f = 0; f < 2; ++f) {
          #pragma unroll
          for (int j = 0; j < 4; ++j)
            rmax[f][j] = fmaxf(fmaxf(s4[f][0][j], s4[f][1][j]),
                               fmaxf(s4[f][2][j], s4[f][3][j]));
          #pragma unroll
          for (int j = 0; j < 4; ++j) {
            rmax[f][j] = fmaxf(rmax[f][j], __shfl_xor(rmax[f][j], 1, 64));
            rmax[f][j] = fmaxf(rmax[f][j], __shfl_xor(rmax[f][j], 2, 64));
            rmax[f][j] = fmaxf(rmax[f][j], __shfl_xor(rmax[f][j], 4, 64));
            rmax[f][j] = fmaxf(rmax[f][j], __shfl_xor(rmax[f][j], 8, 64));
          }
        }
        bool small = true;
        #pragma unroll
        for (int f = 0; f < 2; ++f)
          #pragma unroll
          for (int j = 0; j < 4; ++j)
            small = small && (rmax[f][j] <= mrun[f][j] + 8.0f);
        if (!__all((int)small)) {
          #pragma unroll
          for (int f = 0; f < 2; ++f)
            #pragma unroll
            for (int j = 0; j < 4; ++j) {
              float mn = fmaxf(mrun[f][j], rmax[f][j]);
              float corr = __expf(mrun[f][j] - mn);
              mrun[f][j] = mn;
              lrun[f][j] *= corr;
              #pragma unroll
              for (int nf = 0; nf < 8; ++nf) o[f][nf][j] *= corr;
            }
        }
        #pragma unroll
        for (int f = 0; f < 2; ++f) {
          float rsum[4];
          #pragma unroll
          for (int jf = 0; jf < 4; ++jf)
            #pragma unroll
            for (int j = 0; j < 4; ++j)
              s4[f][jf][j] = __expf(s4[f][jf][j] - mrun[f][j]);
          #pragma unroll
          for (int j = 0; j < 4; ++j) {
            rsum[j] = (s4[f][0][j] + s4[f][1][j]) + (s4[f][2][j] + s4[f][3][j]);
            rsum[j] += __shfl_xor(rsum[j], 1, 64);
            rsum[j] += __shfl_xor(rsum[j], 2, 64);
            rsum[j] += __shfl_xor(rsum[j], 4, 64);
            rsum[j] += __shfl_xor(rsum[j], 8, 64);
            lrun[f][j] += rsum[j];
          }
        }
      }

      // ---- P -> Vt[nxt] (wave-private rows; NO barrier needed)
      {
        u16* Pb = (u16*)Vt[nxt];
        #pragma unroll
        for (int f = 0; f < 2; ++f)
          #pragma unroll
          for (int jf = 0; jf < 4; ++jf)
            #pragma unroll
            for (int j = 0; j < 4; ++j) {
              int prow = wid * 32 + f * 16 + 4 * g + j;
              int pcol = (jf * 16 + l15) ^ (((4 * g + j) & 7) << 3);
              Pb[prow * PADV + pcol] = f2bf(s4[f][jf][j]);
            }
      }
      asm volatile("s_waitcnt lgkmcnt(0)" ::: "memory");
      __builtin_amdgcn_sched_barrier(0);
      short8 pf[2][2];
      #pragma unroll
      for (int f = 0; f < 2; ++f)
        #pragma unroll
        for (int kk = 0; kk < 2; ++kk)
          pf[f][kk] = *(const short8*)&((const u16*)Vt[nxt])[
              (wid * 32 + f * 16 + l15) * PADV + ((kk * 32 + g * 8) ^ ((l15 & 7) << 3))];

      // ---- O += P V from Vt[cur] (vf read shared across both fragments)
      #pragma unroll
      for (int nf = 0; nf < 8; ++nf) {
        #pragma unroll
        for (int kk = 0; kk < 2; ++kk) {
          short8 vf = *(const short8*)&Vt[cur][(nf * 16 + l15) * PADV + kk * 32 + g * 8];
          o[0][nf] = mfma16(pf[0][kk], vf, o[0][nf]);
          o[1][nf] = mfma16(pf[1][kk], vf, o[1][nf]);
        }
      }

      // ---- late V stage into Vt[nxt] (overwrites this wave's P rows —
      // safe: pf already in registers, same-wave DS is in-order)
      if (havenext) {
        const int kvn = (it + 1) * KBLK;
        const u16* vg = qkv + (rb + kvn + vk0) * LD3 + 2 * CC + h * DH + vd0;
        short8 r0 = *(const short8*)vg;
        short8 r1 = *(const short8*)(vg + LD3);
        short8 r2 = *(const short8*)(vg + 2 * LD3);
        short8 r3 = *(const short8*)(vg + 3 * LD3);
        #pragma unroll
        for (int j = 0; j < 8; ++j) {
          ushort4 w;
          w.x = (u16)r0[j]; w.y = (u16)r1[j]; w.z = (u16)r2[j]; w.w = (u16)r3[j];
          *(ushort4*)&Vt[nxt][(vd0 + j) * PADV + vk0] = w;
        }
      }
      asm volatile("s_waitcnt vmcnt(0)" ::: "memory");
      __syncthreads();
    }

    // ---- write back this q-tile
    #pragma unroll
    for (int f = 0; f < 2; ++f) {
      float inv[4];
      #pragma unroll
      for (int j = 0; j < 4; ++j) inv[j] = 1.0f / lrun[f][j];
      #pragma unroll
      for (int nf = 0; nf < 8; ++nf)
        #pragma unroll
        for (int j = 0; j < 4; ++j)
          y[(rb + qt0 + wid * 32 + f * 16 + 4 * g + j) * CC + h * DH + nf * 16 + l15] =
              f2bf(o[f][nf][j] * inv[j]);
    }
  }
}

// ------------------------------------------------------------------ launch
// Workspace layout: non-aliased, 193 MB total.
extern "C" void kernel_launch(void* const* d_in, const int* in_sizes, int n_in,
                              void* d_out, int out_size, void* d_ws, size_t ws_size,
                              hipStream_t stream) {
  const float* x = (const float*)d_in[0];
  const float* Wqkv = (const float*)d_in[1];
  const float* Wproj = (const float*)d_in[2];
  char* ws = (char*)d_ws;
  u16* xb     = (u16*)(ws);                      // 32 MB
  u16* wqkvT  = (u16*)(ws + 33554432);           // 24 MB
  u16* wprojT = (u16*)(ws + 58720256);           // 8 MB
  u16* qkv    = (u16*)(ws + 67108864);           // 96 MB
  u16* y      = (u16*)(ws + 167772160);          // 32 MB
  float2* tab = (float2*)(ws + 201326592);       // 1 MB

  convert_x_kernel<<<4096, 256, 0, stream>>>(x, xb);
  transpose_bf16_kernel<<<dim3(192, 64), dim3(32, 8), 0, stream>>>(Wqkv, wqkvT, CC, N3);
  transpose_bf16_kernel<<<dim3(64, 64), dim3(32, 8), 0, stream>>>(Wproj, wprojT, CC, CC);
  rope_table_kernel<<<512, 256, 0, stream>>>(tab);
  gemm_bt_256<<<dim3(24, 32), 512, 0, stream>>>(xb, wqkvT, (void*)qkv, tab, CC, LD3, 1, 1);
  attn_kernel<<<dim3(8, 64), 256, 0, stream>>>(qkv, y);
  gemm_bt_256<<<dim3(8, 32), 512, 0, stream>>>(y, wprojT, d_out, tab, CC, CC, 0, 0);
}

// Round 19
// 464.068 us; speedup vs baseline: 1.1218x; 1.0288x over previous
//
#include <hip/hip_runtime.h>

// Problem constants
#define BB 4
#define TT 2048
#define CC 2048
#define NHEAD 16
#define DH 128
#define MM (BB * TT)          // 8192 rows
#define N3 (3 * CC)           // 6144
#define LD3 6144

typedef unsigned short u16;
typedef __attribute__((ext_vector_type(8))) short short8;
typedef __attribute__((ext_vector_type(4))) float f32x4;

__device__ __forceinline__ u16 f2bf(float f) {
  unsigned u = __float_as_uint(f);
  u += 0x7fffu + ((u >> 16) & 1u);      // RNE
  return (u16)(u >> 16);
}
__device__ __forceinline__ float bf2f(u16 h) {
  return __uint_as_float(((unsigned)h) << 16);
}

__device__ __forceinline__ void gload_lds16(const void* g, void* l) {
  __builtin_amdgcn_global_load_lds((const __attribute__((address_space(1))) void*)g,
                                   (__attribute__((address_space(3))) void*)l, 16, 0, 0);
}

__device__ __forceinline__ f32x4 mfma16(short8 a, short8 b, f32x4 c) {
  return __builtin_amdgcn_mfma_f32_16x16x32_bf16(a, b, c, 0, 0, 0);
}

// ---------------------------------------------------------------- convert x
__global__ void convert_x_kernel(const float* __restrict__ x, u16* __restrict__ xb) {
  const int total = (MM * CC) / 4;
  const float4* xv = (const float4*)x;
  ushort4* ov = (ushort4*)xb;
  for (int i = blockIdx.x * blockDim.x + threadIdx.x; i < total; i += gridDim.x * blockDim.x) {
    float4 v = xv[i];
    ushort4 o;
    o.x = f2bf(v.x); o.y = f2bf(v.y); o.z = f2bf(v.z); o.w = f2bf(v.w);
    ov[i] = o;
  }
}

// ------------------------------------------- transpose + convert W -> W^T bf16
__global__ void transpose_bf16_kernel(const float* __restrict__ W, u16* __restrict__ Wt,
                                      int rows, int cols) {
  __shared__ float tile[32][33];
  const int n0 = blockIdx.x * 32, k0 = blockIdx.y * 32;
  const int tx = threadIdx.x, ty = threadIdx.y;   // (32, 8)
  #pragma unroll
  for (int i = 0; i < 4; ++i)
    tile[ty + 8 * i][tx] = W[(size_t)(k0 + ty + 8 * i) * cols + n0 + tx];
  __syncthreads();
  #pragma unroll
  for (int i = 0; i < 4; ++i)
    Wt[(size_t)(n0 + ty + 8 * i) * rows + k0 + tx] = f2bf(tile[tx][ty + 8 * i]);
}

// ---------------------------------------------------------------- rope table
__global__ void rope_table_kernel(float2* __restrict__ tab) {
  int idx = blockIdx.x * 256 + threadIdx.x;     // T*64 entries
  int t = idx >> 6, f = idx & 63;
  float freq = expf(-0.14391156831f * (float)f);   // 10000^(-f/64)
  float ang = (float)t * freq;
  float s, c;
  sincosf(ang, &s, &c);
  tab[idx] = make_float2(c, s);
}

// ------------------------------------------------------------------- GEMM
// R19: XCD-ownership remap (R18: loads L2/L3-resident, FETCH 152MB) + the
// classic ONE-barrier-per-K-tile loop. With L2-resident loads the full
// vmcnt(0) drain (the documented m97 weakness at HBM latency) costs ~250cy
// issued >=3 phases earlier — nearly free. No intra-tile barriers: waves
// drift, so one wave's MFMA overlaps another's ds_reads (m114). WAR-safe:
// all cur-reads feed MFMAs whose compiler lgkmcnt waits precede the
// barrier; each wave drains its own stages (vmcnt(0)) before the barrier.
#define TILE_B 32768   // bytes of one [256][64]-bf16 LDS tile

__device__ __forceinline__ int swz47(int x) { return x ^ (((x >> 7) & 7) << 4); }

__device__ __forceinline__ void stage_chunk(const u16* __restrict__ src, int K, int k0,
                                            char* ldsTile, int kind, int wid, int lane) {
  // kind: 0=A-q1rows 1=A-q3rows 2=B-lo 3=B-hi ; 2 loads/thread = 16KB chunk
  #pragma unroll
  for (int c = 0; c < 2; ++c) {
    int x;
    if (kind < 2) {
      x = (kind ? 8192 : 0) + c * 16384 + wid * 1024 + lane * 16;
    } else {
      int wl = wid * 2 + c;
      x = ((kind == 3) ? 4096 : 0) + (wl >> 2) * 8192 + (wl & 3) * 1024 + lane * 16;
    }
    int l = swz47(x);                      // logical byte (involution, row-preserving)
    int r = l >> 7;                        // row 0..255
    int ce = (l >> 1) & 63;                // col element 0..63 (16B-aligned)
    gload_lds16(src + (size_t)r * K + k0 + ce, ldsTile + (x - lane * 16));
  }
}

__global__ __launch_bounds__(512, 2) void gemm_bt_256(const u16* __restrict__ A,
                                                      const u16* __restrict__ Bt,
                                                      void* __restrict__ Cout,
                                                      const float2* __restrict__ tab,
                                                      int K, int ldc, int out_bf16,
                                                      int rope_mode) {
  __shared__ __align__(16) char As[2][TILE_B];
  __shared__ __align__(16) char Bs[2][TILE_B];
  const int tid = threadIdx.x;
  const int wid = tid >> 6, lane = tid & 63;
  const int l15 = lane & 15, g = lane >> 4;
  const int wr = wid >> 2, wc = wid & 3;          // 2M x 4N wave grid
  // XCD ownership remap (bijective; gridDim.y % 8 == 0 at both call sites)
  const int orig = blockIdx.y * gridDim.x + blockIdx.x;
  const int xcd = orig & 7;
  const int local = orig >> 3;
  const int gy = gridDim.y >> 3;                  // by-rows per XCD (=4)
  const int bx = local / gy;
  const int by = xcd * gy + (local - bx * gy);
  const int row0 = by * 256, col0 = bx * 256;

  const u16* Ab = A + (size_t)row0 * K;
  const u16* Bb = Bt + (size_t)col0 * K;

  f32x4 acc[8][4];
  #pragma unroll
  for (int m = 0; m < 8; ++m)
    #pragma unroll
    for (int n = 0; n < 4; ++n) acc[m][n] = (f32x4){0.f, 0.f, 0.f, 0.f};

  // pair-friendly B-column map
  int bcol[4];
  #pragma unroll
  for (int n = 0; n < 4; ++n)
    bcol[n] = (wc & 1) * 32 + (wc >> 1) * 128 + ((n >> 1) << 6) + ((n & 1) << 4);

  // per-thread logical byte bases for fragment reads
  const int abase = (wr * 128 + l15) * 128 + g * 16;   // + m*2048 + ks*64

  // ---- prologue: tile 0 fully staged into buf 0
  stage_chunk(Ab, K, 0, As[0], 0, wid, lane);
  stage_chunk(Bb, K, 0, Bs[0], 2, wid, lane);
  stage_chunk(Bb, K, 0, Bs[0], 3, wid, lane);
  stage_chunk(Ab, K, 0, As[0], 1, wid, lane);
  asm volatile("s_waitcnt vmcnt(0)" ::: "memory");
  __builtin_amdgcn_s_barrier();

  const int nt = K >> 6;
  short8 a[4][2], blo[2][2], bhi[2][2];
  for (int kt = 0; kt < nt; ++kt) {
    const int cur = kt & 1, nx = cur ^ 1;
    const bool hn = (kt + 1) < nt;
    const int kn = (kt + 1) << 6;
    const char* At = As[cur];
    const char* Btl = Bs[cur];

    // ---- q1 (m0-3 x n0-1) ; stage kind0 of tile kt+1
    #pragma unroll
    for (int m = 0; m < 4; ++m)
      #pragma unroll
      for (int ks = 0; ks < 2; ++ks)
        a[m][ks] = *(const short8*)(At + swz47(abase + m * 2048 + ks * 64));
    #pragma unroll
    for (int n = 0; n < 2; ++n)
      #pragma unroll
      for (int ks = 0; ks < 2; ++ks)
        blo[n][ks] = *(const short8*)(Btl +
            swz47((bcol[n] + l15) * 128 + g * 16 + ks * 64));
    if (hn) stage_chunk(Ab, K, kn, As[nx], 0, wid, lane);
    __builtin_amdgcn_s_setprio(1);
    #pragma unroll
    for (int m = 0; m < 4; ++m)
      #pragma unroll
      for (int n = 0; n < 2; ++n)
        #pragma unroll
        for (int ks = 0; ks < 2; ++ks)
          acc[m][n] = mfma16(a[m][ks], blo[n][ks], acc[m][n]);
    __builtin_amdgcn_s_setprio(0);

    // ---- q2 (m0-3 x n2-3) ; stage kind2 (B-lo) of tile kt+1
    #pragma unroll
    for (int n = 0; n < 2; ++n)
      #pragma unroll
      for (int ks = 0; ks < 2; ++ks)
        bhi[n][ks] = *(const short8*)(Btl +
            swz47((bcol[n + 2] + l15) * 128 + g * 16 + ks * 64));
    if (hn) stage_chunk(Bb, K, kn, Bs[nx], 2, wid, lane);
    __builtin_amdgcn_s_setprio(1);
    #pragma unroll
    for (int m = 0; m < 4; ++m)
      #pragma unroll
      for (int n = 0; n < 2; ++n)
        #pragma unroll
        for (int ks = 0; ks < 2; ++ks)
          acc[m][n + 2] = mfma16(a[m][ks], bhi[n][ks], acc[m][n + 2]);
    __builtin_amdgcn_s_setprio(0);

    // ---- q3 (m4-7 x n0-1) ; stage kind3 (B-hi) of tile kt+1
    #pragma unroll
    for (int m = 0; m < 4; ++m)
      #pragma unroll
      for (int ks = 0; ks < 2; ++ks)
        a[m][ks] = *(const short8*)(At + swz47(abase + (m + 4) * 2048 + ks * 64));
    if (hn) stage_chunk(Bb, K, kn, Bs[nx], 3, wid, lane);
    __builtin_amdgcn_s_setprio(1);
    #pragma unroll
    for (int m = 0; m < 4; ++m)
      #pragma unroll
      for (int n = 0; n < 2; ++n)
        #pragma unroll
        for (int ks = 0; ks < 2; ++ks)
          acc[m + 4][n] = mfma16(a[m][ks], blo[n][ks], acc[m + 4][n]);
    __builtin_amdgcn_s_setprio(0);

    // ---- q4 (m4-7 x n2-3) ; stage kind1 (A-q3rows) of tile kt+1
    if (hn) stage_chunk(Ab, K, kn, As[nx], 1, wid, lane);
    __builtin_amdgcn_s_setprio(1);
    #pragma unroll
    for (int m = 0; m < 4; ++m)
      #pragma unroll
      for (int n = 0; n < 2; ++n)
        #pragma unroll
        for (int ks = 0; ks < 2; ++ks)
          acc[m + 4][n + 2] = mfma16(a[m][ks], bhi[n][ks], acc[m + 4][n + 2]);
    __builtin_amdgcn_s_setprio(0);

    // ---- tile end: drain own stages (L2-resident, issued >=2 phases ago),
    // then one barrier publishes buf[nx] and releases buf[cur] for writing.
    asm volatile("s_waitcnt vmcnt(0)" ::: "memory");
    __builtin_amdgcn_s_barrier();
  }

  // ---- epilogue
  if (out_bf16) {
    u16* Cb = (u16*)Cout;
    if (rope_mode && col0 < 4096) {
      // q or k tile: rotate pairs (n, n+2) in-register, then store
      const bool isq = (col0 < 2048);
      const float qs = isq ? 0.08838834764831845f : 1.0f;
      #pragma unroll
      for (int m = 0; m < 8; ++m)
        #pragma unroll
        for (int n = 0; n < 2; ++n) {
          int colL = col0 + bcol[n] + l15;
          int f = (wc & 1) * 32 + ((n & 1) << 4) + l15;   // = colL % 128, < 64
          #pragma unroll
          for (int j = 0; j < 4; ++j) {
            int row = row0 + wr * 128 + m * 16 + 4 * g + j;
            float2 cs = tab[((row & (TT - 1)) << 6) + f];
            float x1 = acc[m][n][j], x2 = acc[m][n + 2][j];
            float o1 = (x1 * cs.x - x2 * cs.y) * qs;
            float o2 = (x2 * cs.x + x1 * cs.y) * qs;
            Cb[(size_t)row * ldc + colL] = f2bf(o1);
            Cb[(size_t)row * ldc + colL + 64] = f2bf(o2);
          }
        }
    } else {
      #pragma unroll
      for (int m = 0; m < 8; ++m)
        #pragma unroll
        for (int n = 0; n < 4; ++n) {
          int row = row0 + wr * 128 + m * 16 + 4 * g;
          int col = col0 + bcol[n] + l15;
          #pragma unroll
          for (int j = 0; j < 4; ++j)
            Cb[(size_t)(row + j) * ldc + col] = f2bf(acc[m][n][j]);
        }
    }
  } else {
    float* Cf = (float*)Cout;
    #pragma unroll
    for (int m = 0; m < 8; ++m)
      #pragma unroll
      for (int n = 0; n < 4; ++n) {
        int row = row0 + wr * 128 + m * 16 + 4 * g;
        int col = col0 + bcol[n] + l15;
        #pragma unroll
        for (int j = 0; j < 4; ++j)
          Cf[(size_t)(row + j) * ldc + col] = acc[m][n][j];
      }
  }
}

// ---------------------------------------------------------------- attention
// R17-exact: QBLK=128, diagonal pairing, 512 blocks, 2 blocks/CU, T13
// defer-max, P round-trips through Vt[nxt] (wave-private rows).
#define QBLK 128
#define KBLK 64
#define PADV 72

__global__ __launch_bounds__(256, 2) void attn_kernel(const u16* __restrict__ qkv,
                                                      u16* __restrict__ y) {
  __shared__ __align__(16) u16 Ks[2][KBLK * 128];   // K tiles (swizzled)
  __shared__ __align__(16) u16 Vt[2][DH * PADV];    // V^T [d][kv] / P scratch
  const int tid = threadIdx.x;
  const int wid = tid >> 6, lane = tid & 63;
  const int l15 = lane & 15, g = lane >> 4;
  const int b = blockIdx.y >> 4, h = blockIdx.y & 15;
  const size_t rb = (size_t)b * TT;
  const int vk0 = (tid & 15) * 4, vd0 = (tid >> 4) * 8;   // V-staging assignment

  for (int half = 0; half < 2; ++half) {
    const int qt0 = (half ? (15 - (int)blockIdx.x) : (int)blockIdx.x) * QBLK;

    // ---- Q fragments straight from global (one-time; rows 12KB apart)
    short8 qf[2][4];
    {
      const u16* qbase = qkv + (rb + qt0 + wid * 32 + l15) * LD3 + h * DH;
      #pragma unroll
      for (int f = 0; f < 2; ++f)
        #pragma unroll
        for (int kk = 0; kk < 4; ++kk)
          qf[f][kk] = *(const short8*)(qbase + f * 16 * LD3 + kk * 32 + g * 8);
    }

    // ---- prologue: stage K(tile0) -> Ks[0], V(tile0) -> Vt[0]
    {
      const u16* kbase = qkv + (rb)*LD3 + CC + h * DH;
      #pragma unroll
      for (int c = 0; c < 4; ++c) {
        int chunk = c * 256 + tid;
        int r = chunk >> 4, s = chunk & 15;
        gload_lds16(kbase + (size_t)r * LD3 + (size_t)((s ^ (r & 7)) * 8),
                    &Ks[0][(c * 256 + wid * 64) * 8]);
      }
      const u16* vg = qkv + (rb + vk0) * LD3 + 2 * CC + h * DH + vd0;
      short8 r0 = *(const short8*)vg;
      short8 r1 = *(const short8*)(vg + LD3);
      short8 r2 = *(const short8*)(vg + 2 * LD3);
      short8 r3 = *(const short8*)(vg + 3 * LD3);
      #pragma unroll
      for (int j = 0; j < 8; ++j) {
        ushort4 w;
        w.x = (u16)r0[j]; w.y = (u16)r1[j]; w.z = (u16)r2[j]; w.w = (u16)r3[j];
        *(ushort4*)&Vt[0][(vd0 + j) * PADV + vk0] = w;
      }
    }
    asm volatile("s_waitcnt vmcnt(0)" ::: "memory");
    __syncthreads();

    f32x4 o[2][8];
    float mrun[2][4], lrun[2][4];
    #pragma unroll
    for (int f = 0; f < 2; ++f) {
      #pragma unroll
      for (int nf = 0; nf < 8; ++nf) o[f][nf] = (f32x4){0.f, 0.f, 0.f, 0.f};
      #pragma unroll
      for (int j = 0; j < 4; ++j) { mrun[f][j] = -1e30f; lrun[f][j] = 0.f; }
    }

    const int nt = qt0 / KBLK + 2;         // kv tiles (last two intersect diagonal)
    for (int it = 0; it < nt; ++it) {
      const int cur = it & 1, nxt = cur ^ 1;
      const bool havenext = (it + 1) < nt;
      if (havenext) {
        const int kvn = (it + 1) * KBLK;
        const u16* kbase = qkv + (rb + kvn) * LD3 + CC + h * DH;
        #pragma unroll
        for (int c = 0; c < 4; ++c) {
          int chunk = c * 256 + tid;
          int r = chunk >> 4, s = chunk & 15;
          gload_lds16(kbase + (size_t)r * LD3 + (size_t)((s ^ (r & 7)) * 8),
                      &Ks[nxt][(c * 256 + wid * 64) * 8]);
        }
      }

      // ---- S = Q K^T from Ks[cur] (q pre-scaled by 1/sqrt(D))
      f32x4 s4[2][4];
      #pragma unroll
      for (int f = 0; f < 2; ++f)
        #pragma unroll
        for (int jf = 0; jf < 4; ++jf) s4[f][jf] = (f32x4){0.f, 0.f, 0.f, 0.f};
      #pragma unroll
      for (int jf = 0; jf < 4; ++jf) {
        int krow = jf * 16 + l15;
        #pragma unroll
        for (int kk = 0; kk < 4; ++kk) {
          short8 kf = *(const short8*)((const char*)Ks[cur] + krow * 256 +
                                       ((kk * 64 + g * 16) ^ ((l15 & 7) << 4)));
          s4[0][jf] = mfma16(qf[0][kk], kf, s4[0][jf]);
          s4[1][jf] = mfma16(qf[1][kk], kf, s4[1][jf]);
        }
      }
      // causal mask: last two tiles intersect the diagonal of this q-block
      if (it >= nt - 2) {
        const int kvb = it * KBLK - qt0;   // kv offset relative to q-block base
        #pragma unroll
        for (int f = 0; f < 2; ++f)
          #pragma unroll
          for (int jf = 0; jf < 4; ++jf)
            #pragma unroll
            for (int j = 0; j < 4; ++j)
              if (kvb + jf * 16 + l15 > wid * 32 + f * 16 + 4 * g + j)
                s4[f][jf][j] = -1e30f;
      }
      // ---- online softmax with T13 defer-max (THR=8)
      {
        float rmax[2][4];
        #pragma unroll
        for (int f = 0; f < 2; ++f) {
          #pragma unroll
          for (int j = 0; j < 4; ++j)
            rmax[f][j] = fmaxf(fmaxf(s4[f][0][j], s4[f][1][j]),
                               fmaxf(s4[f][2][j], s4[f][3][j]));
          #pragma unroll
          for (int j = 0; j < 4; ++j) {
            rmax[f][j] = fmaxf(rmax[f][j], __shfl_xor(rmax[f][j], 1, 64));
            rmax[f][j] = fmaxf(rmax[f][j], __shfl_xor(rmax[f][j], 2, 64));
            rmax[f][j] = fmaxf(rmax[f][j], __shfl_xor(rmax[f][j], 4, 64));
            rmax[f][j] = fmaxf(rmax[f][j], __shfl_xor(rmax[f][j], 8, 64));
          }
        }
        bool small = true;
        #pragma unroll
        for (int f = 0; f < 2; ++f)
          #pragma unroll
          for (int j = 0; j < 4; ++j)
            small = small && (rmax[f][j] <= mrun[f][j] + 8.0f);
        if (!__all((int)small)) {
          #pragma unroll
          for (int f = 0; f < 2; ++f)
            #pragma unroll
            for (int j = 0; j < 4; ++j) {
              float mn = fmaxf(mrun[f][j], rmax[f][j]);
              float corr = __expf(mrun[f][j] - mn);
              mrun[f][j] = mn;
              lrun[f][j] *= corr;
              #pragma unroll
              for (int nf = 0; nf < 8; ++nf) o[f][nf][j] *= corr;
            }
        }
        #pragma unroll
        for (int f = 0; f < 2; ++f) {
          float rsum[4];
          #pragma unroll
          for (int jf = 0; jf < 4; ++jf)
            #pragma unroll
            for (int j = 0; j < 4; ++j)
              s4[f][jf][j] = __expf(s4[f][jf][j] - mrun[f][j]);
          #pragma unroll
          for (int j = 0; j < 4; ++j) {
            rsum[j] = (s4[f][0][j] + s4[f][1][j]) + (s4[f][2][j] + s4[f][3][j]);
            rsum[j] += __shfl_xor(rsum[j], 1, 64);
            rsum[j] += __shfl_xor(rsum[j], 2, 64);
            rsum[j] += __shfl_xor(rsum[j], 4, 64);
            rsum[j] += __shfl_xor(rsum[j], 8, 64);
            lrun[f][j] += rsum[j];
          }
        }
      }

      // ---- P -> Vt[nxt] (wave-private rows; NO barrier needed)
      {
        u16* Pb = (u16*)Vt[nxt];
        #pragma unroll
        for (int f = 0; f < 2; ++f)
          #pragma unroll
          for (int jf = 0; jf < 4; ++jf)
            #pragma unroll
            for (int j = 0; j < 4; ++j) {
              int prow = wid * 32 + f * 16 + 4 * g + j;
              int pcol = (jf * 16 + l15) ^ (((4 * g + j) & 7) << 3);
              Pb[prow * PADV + pcol] = f2bf(s4[f][jf][j]);
            }
      }
      asm volatile("s_waitcnt lgkmcnt(0)" ::: "memory");
      __builtin_amdgcn_sched_barrier(0);
      short8 pf[2][2];
      #pragma unroll
      for (int f = 0; f < 2; ++f)
        #pragma unroll
        for (int kk = 0; kk < 2; ++kk)
          pf[f][kk] = *(const short8*)&((const u16*)Vt[nxt])[
              (wid * 32 + f * 16 + l15) * PADV + ((kk * 32 + g * 8) ^ ((l15 & 7) << 3))];

      // ---- O += P V from Vt[cur] (vf read shared across both fragments)
      #pragma unroll
      for (int nf = 0; nf < 8; ++nf) {
        #pragma unroll
        for (int kk = 0; kk < 2; ++kk) {
          short8 vf = *(const short8*)&Vt[cur][(nf * 16 + l15) * PADV + kk * 32 + g * 8];
          o[0][nf] = mfma16(pf[0][kk], vf, o[0][nf]);
          o[1][nf] = mfma16(pf[1][kk], vf, o[1][nf]);
        }
      }

      // ---- late V stage into Vt[nxt] (overwrites this wave's P rows —
      // safe: pf already in registers, same-wave DS is in-order)
      if (havenext) {
        const int kvn = (it + 1) * KBLK;
        const u16* vg = qkv + (rb + kvn + vk0) * LD3 + 2 * CC + h * DH + vd0;
        short8 r0 = *(const short8*)vg;
        short8 r1 = *(const short8*)(vg + LD3);
        short8 r2 = *(const short8*)(vg + 2 * LD3);
        short8 r3 = *(const short8*)(vg + 3 * LD3);
        #pragma unroll
        for (int j = 0; j < 8; ++j) {
          ushort4 w;
          w.x = (u16)r0[j]; w.y = (u16)r1[j]; w.z = (u16)r2[j]; w.w = (u16)r3[j];
          *(ushort4*)&Vt[nxt][(vd0 + j) * PADV + vk0] = w;
        }
      }
      asm volatile("s_waitcnt vmcnt(0)" ::: "memory");
      __syncthreads();
    }

    // ---- write back this q-tile
    #pragma unroll
    for (int f = 0; f < 2; ++f) {
      float inv[4];
      #pragma unroll
      for (int j = 0; j < 4; ++j) inv[j] = 1.0f / lrun[f][j];
      #pragma unroll
      for (int nf = 0; nf < 8; ++nf)
        #pragma unroll
        for (int j = 0; j < 4; ++j)
          y[(rb + qt0 + wid * 32 + f * 16 + 4 * g + j) * CC + h * DH + nf * 16 + l15] =
              f2bf(o[f][nf][j] * inv[j]);
    }
  }
}

// ------------------------------------------------------------------ launch
// Workspace layout: non-aliased, 193 MB total.
extern "C" void kernel_launch(void* const* d_in, const int* in_sizes, int n_in,
                              void* d_out, int out_size, void* d_ws, size_t ws_size,
                              hipStream_t stream) {
  const float* x = (const float*)d_in[0];
  const float* Wqkv = (const float*)d_in[1];
  const float* Wproj = (const float*)d_in[2];
  char* ws = (char*)d_ws;
  u16* xb     = (u16*)(ws);                      // 32 MB
  u16* wqkvT  = (u16*)(ws + 33554432);           // 24 MB
  u16* wprojT = (u16*)(ws + 58720256);           // 8 MB
  u16* qkv    = (u16*)(ws + 67108864);           // 96 MB
  u16* y      = (u16*)(ws + 167772160);          // 32 MB
  float2* tab = (float2*)(ws + 201326592);       // 1 MB

  convert_x_kernel<<<4096, 256, 0, stream>>>(x, xb);
  transpose_bf16_kernel<<<dim3(192, 64), dim3(32, 8), 0, stream>>>(Wqkv, wqkvT, CC, N3);
  transpose_bf16_kernel<<<dim3(64, 64), dim3(32, 8), 0, stream>>>(Wproj, wprojT, CC, CC);
  rope_table_kernel<<<512, 256, 0, stream>>>(tab);
  gemm_bt_256<<<dim3(24, 32), 512, 0, stream>>>(xb, wqkvT, (void*)qkv, tab, CC, LD3, 1, 1);
  attn_kernel<<<dim3(8, 64), 256, 0, stream>>>(qkv, y);
  gemm_bt_256<<<dim3(8, 32), 512, 0, stream>>>(y, wprojT, d_out, tab, CC, CC, 0, 0);
}